// Round 1
// baseline (869.293 us; speedup 1.0000x reference)
//
#include <hip/hip_runtime.h>
#include <hip/hip_bf16.h>

#define B_   2
#define S_   2048
#define D_   512
#define M_   64
#define T_   2112
#define BT_  4224
#define H_   8
#define WIN_ 512

__device__ __forceinline__ float siluf(float x) {
    float s = 1.0f / (1.0f + expf(-x));
    return x * s;
}
__device__ __forceinline__ float dsiluf(float x) {
    float s = 1.0f / (1.0f + expf(-x));
    return s * (1.0f + x * (1.0f - s));
}

// ---------------- build xm = concat(meta, x) ----------------
__global__ void build_xm_kernel(const float* __restrict__ x, const float* __restrict__ meta,
                                float* __restrict__ xm) {
    int idx = blockIdx.x * 256 + threadIdx.x;   // float4 index over BT_*128
    int d4  = idx & 127;
    int row = idx >> 7;
    int b   = row / T_;
    int t   = row - b * T_;
    float4 v;
    if (t < M_) v = ((const float4*)meta)[t * 128 + d4];
    else        v = ((const float4*)x)[((size_t)b * S_ + (t - M_)) * 128 + d4];
    ((float4*)xm)[idx] = v;
}

// ---------------- alr = sigmoid(xm @ w_lr^T) * 0.01 ----------------
__global__ void alr_kernel(const float* __restrict__ xm, const float* __restrict__ wlr,
                           float* __restrict__ alr) {
    int r = blockIdx.x * 4 + (threadIdx.x >> 6);
    int lane = threadIdx.x & 63;
    const float* row = xm + (size_t)r * D_;
    float s = 0.f;
#pragma unroll
    for (int k = 0; k < 8; ++k) s = fmaf(row[lane + k * 64], wlr[lane + k * 64], s);
#pragma unroll
    for (int off = 32; off >= 1; off >>= 1) s += __shfl_xor(s, off, 64);
    if (lane == 0) alr[r] = 0.01f / (1.0f + expf(-s));
}

// ---------------- SGEMM: C[4224,512] , K=512 ----------------
// LAYB: 0 = NT (Bm is [512,512] row-major, use Bm[n][k]) ; 1 = NN (use Bm[k][n])
// EPI:  0 plain C=acc ; 1 H = R + silu(acc), optional Z=acc ; 2 C = R + acc ; 3 row-filtered store (drop meta rows)
template<int LAYB, int EPI>
__global__ __launch_bounds__(256)
void gemm512(const float* __restrict__ A, const float* __restrict__ Bm,
             float* __restrict__ C, const float* __restrict__ R, float* __restrict__ Z) {
    __shared__ float As[16][68];
    __shared__ float Bs[16][68];
    int tid = threadIdx.x;
    int m0 = blockIdx.x * 64, n0 = blockIdx.y * 64;
    int alm = tid >> 2;              // 0..63
    int alk = (tid & 3) << 2;        // 0,4,8,12
    int blr = tid >> 4;              // 0..15  (NN k-row)
    int blc = (tid & 15) << 2;       // 0..60  (NN n-col)
    int tm = (tid & 15) << 2;
    int tn = (tid >> 4) << 2;
    float acc[4][4] = {};
    for (int k0 = 0; k0 < 512; k0 += 16) {
        float4 av = *(const float4*)&A[(size_t)(m0 + alm) * 512 + k0 + alk];
        float4 bv;
        if (LAYB == 0) bv = *(const float4*)&Bm[(size_t)(n0 + alm) * 512 + k0 + alk];
        else           bv = *(const float4*)&Bm[(size_t)(k0 + blr) * 512 + n0 + blc];
        __syncthreads();
        As[alk + 0][alm] = av.x; As[alk + 1][alm] = av.y;
        As[alk + 2][alm] = av.z; As[alk + 3][alm] = av.w;
        if (LAYB == 0) {
            Bs[alk + 0][alm] = bv.x; Bs[alk + 1][alm] = bv.y;
            Bs[alk + 2][alm] = bv.z; Bs[alk + 3][alm] = bv.w;
        } else {
            *(float4*)&Bs[blr][blc] = bv;
        }
        __syncthreads();
#pragma unroll
        for (int kk = 0; kk < 16; ++kk) {
            float4 a = *(const float4*)&As[kk][tm];
            float4 b = *(const float4*)&Bs[kk][tn];
            acc[0][0] = fmaf(a.x,b.x,acc[0][0]); acc[0][1] = fmaf(a.x,b.y,acc[0][1]);
            acc[0][2] = fmaf(a.x,b.z,acc[0][2]); acc[0][3] = fmaf(a.x,b.w,acc[0][3]);
            acc[1][0] = fmaf(a.y,b.x,acc[1][0]); acc[1][1] = fmaf(a.y,b.y,acc[1][1]);
            acc[1][2] = fmaf(a.y,b.z,acc[1][2]); acc[1][3] = fmaf(a.y,b.w,acc[1][3]);
            acc[2][0] = fmaf(a.z,b.x,acc[2][0]); acc[2][1] = fmaf(a.z,b.y,acc[2][1]);
            acc[2][2] = fmaf(a.z,b.z,acc[2][2]); acc[2][3] = fmaf(a.z,b.w,acc[2][3]);
            acc[3][0] = fmaf(a.w,b.x,acc[3][0]); acc[3][1] = fmaf(a.w,b.y,acc[3][1]);
            acc[3][2] = fmaf(a.w,b.z,acc[3][2]); acc[3][3] = fmaf(a.w,b.w,acc[3][3]);
        }
    }
#pragma unroll
    for (int i = 0; i < 4; ++i) {
        int row = m0 + tm + i;
        size_t off = (size_t)row * 512 + n0 + tn;
        float4 o; o.x = acc[i][0]; o.y = acc[i][1]; o.z = acc[i][2]; o.w = acc[i][3];
        if (EPI == 0) {
            *(float4*)&C[off] = o;
        } else if (EPI == 1) {
            float4 r4 = *(const float4*)&R[off];
            float4 hh;
            hh.x = r4.x + siluf(o.x); hh.y = r4.y + siluf(o.y);
            hh.z = r4.z + siluf(o.z); hh.w = r4.w + siluf(o.w);
            *(float4*)&C[off] = hh;
            if (Z != nullptr) *(float4*)&Z[off] = o;
        } else if (EPI == 2) {
            float4 r4 = *(const float4*)&R[off];
            o.x += r4.x; o.y += r4.y; o.z += r4.z; o.w += r4.w;
            *(float4*)&C[off] = o;
        } else {
            int b = row / T_;
            int t = row - b * T_;
            if (t >= M_) {
                size_t oo = ((size_t)b * S_ + (t - M_)) * 512 + n0 + tn;
                *(float4*)&C[oo] = o;
            }
        }
    }
}

// ---------------- TN GEMM for dW: C[512,512] = sum_t A[t,m]*B[t,n], split-K partials ----------------
__global__ __launch_bounds__(256)
void gemm_tn(const float* __restrict__ A, const float* __restrict__ Bm, float* __restrict__ Cpart) {
    __shared__ float As[16][68];
    __shared__ float Bs[16][68];
    int tid = threadIdx.x;
    int m0 = blockIdx.x * 64, n0 = blockIdx.y * 64;
    int kbase = blockIdx.z * 528;          // 4224 / 8 slices
    int lr = tid >> 4, lc = (tid & 15) << 2;
    int tm = (tid & 15) << 2, tn = (tid >> 4) << 2;
    float acc[4][4] = {};
    for (int kt = 0; kt < 33; ++kt) {
        int k0 = kbase + kt * 16;
        float4 av = *(const float4*)&A[(size_t)(k0 + lr) * 512 + m0 + lc];
        float4 bv = *(const float4*)&Bm[(size_t)(k0 + lr) * 512 + n0 + lc];
        __syncthreads();
        *(float4*)&As[lr][lc] = av;
        *(float4*)&Bs[lr][lc] = bv;
        __syncthreads();
#pragma unroll
        for (int kk = 0; kk < 16; ++kk) {
            float4 a = *(const float4*)&As[kk][tm];
            float4 b = *(const float4*)&Bs[kk][tn];
            acc[0][0] = fmaf(a.x,b.x,acc[0][0]); acc[0][1] = fmaf(a.x,b.y,acc[0][1]);
            acc[0][2] = fmaf(a.x,b.z,acc[0][2]); acc[0][3] = fmaf(a.x,b.w,acc[0][3]);
            acc[1][0] = fmaf(a.y,b.x,acc[1][0]); acc[1][1] = fmaf(a.y,b.y,acc[1][1]);
            acc[1][2] = fmaf(a.y,b.z,acc[1][2]); acc[1][3] = fmaf(a.y,b.w,acc[1][3]);
            acc[2][0] = fmaf(a.z,b.x,acc[2][0]); acc[2][1] = fmaf(a.z,b.y,acc[2][1]);
            acc[2][2] = fmaf(a.z,b.z,acc[2][2]); acc[2][3] = fmaf(a.z,b.w,acc[2][3]);
            acc[3][0] = fmaf(a.w,b.x,acc[3][0]); acc[3][1] = fmaf(a.w,b.y,acc[3][1]);
            acc[3][2] = fmaf(a.w,b.z,acc[3][2]); acc[3][3] = fmaf(a.w,b.w,acc[3][3]);
        }
    }
    float* C = Cpart + (size_t)blockIdx.z * 262144;
#pragma unroll
    for (int i = 0; i < 4; ++i) {
        float4 o; o.x = acc[i][0]; o.y = acc[i][1]; o.z = acc[i][2]; o.w = acc[i][3];
        *(float4*)&C[(size_t)(m0 + tm + i) * 512 + n0 + tn] = o;
    }
}

// ---------------- dp = (2*alr/D)*(h1 + silu(z1) - v); dz1 = dp * silu'(z1) (in-place over z1) ----------------
__global__ void dpdz1_kernel(const float* __restrict__ h1, float* __restrict__ z1,
                             const float* __restrict__ vv, const float* __restrict__ alr,
                             float* __restrict__ dp) {
    int idx = blockIdx.x * 256 + threadIdx.x;   // float4 index
    int r = idx >> 7;
    float c = (2.0f / 512.0f) * alr[r];
    float4 z4 = ((const float4*)z1)[idx];
    float4 h4 = ((const float4*)h1)[idx];
    float4 v4 = ((const float4*)vv)[idx];
    float4 dp4, dz4;
    {
        float s = 1.f/(1.f+expf(-z4.x)); float d = c*(h4.x + z4.x*s - v4.x);
        dp4.x = d; dz4.x = d * (s*(1.f + z4.x*(1.f-s)));
    }{
        float s = 1.f/(1.f+expf(-z4.y)); float d = c*(h4.y + z4.y*s - v4.y);
        dp4.y = d; dz4.y = d * (s*(1.f + z4.y*(1.f-s)));
    }{
        float s = 1.f/(1.f+expf(-z4.z)); float d = c*(h4.z + z4.z*s - v4.z);
        dp4.z = d; dz4.z = d * (s*(1.f + z4.z*(1.f-s)));
    }{
        float s = 1.f/(1.f+expf(-z4.w)); float d = c*(h4.w + z4.w*s - v4.w);
        dp4.w = d; dz4.w = d * (s*(1.f + z4.w*(1.f-s)));
    }
    ((float4*)dp)[idx] = dp4;
    ((float4*)z1)[idx] = dz4;
}

// ---------------- dz0 = dh1 * silu'(z0) (in-place over z0) ----------------
__global__ void dz0_kernel(const float* __restrict__ dh1, float* __restrict__ z0) {
    int idx = blockIdx.x * 256 + threadIdx.x;
    float4 z4 = ((const float4*)z0)[idx];
    float4 g4 = ((const float4*)dh1)[idx];
    float4 o;
    o.x = g4.x * dsiluf(z4.x); o.y = g4.y * dsiluf(z4.y);
    o.z = g4.z * dsiluf(z4.z); o.w = g4.w * dsiluf(z4.w);
    ((float4*)z0)[idx] = o;
}

// ---------------- AdamW first step: Wn = W*(1-1e-5) - 1e-3*g/(|g|+1e-8), g = (sum of 8 partials)/16 ----------------
__global__ void adam_kernel(const float* __restrict__ W, const float* __restrict__ dWp,
                            float* __restrict__ Wn) {
    int idx = blockIdx.x * 256 + threadIdx.x;   // 0..524287
    int layer = idx >> 18;
    int i = idx & 262143;
    const float* base = dWp + (size_t)layer * 8 * 262144 + i;
    float g = 0.f;
#pragma unroll
    for (int z = 0; z < 8; ++z) g += base[(size_t)z * 262144];
    g *= (1.0f / 16.0f);
    float w = W[idx];
    Wn[idx] = w * (1.0f - 1e-5f) - 1e-3f * g / (fabsf(g) + 1e-8f);
}

// ---------------- sliding-window attention: 64 queries/block, 4 lanes per query ----------------
__global__ __launch_bounds__(256)
void swa_kernel(const float* __restrict__ qh, const float* __restrict__ kh,
                const float* __restrict__ vh, float* __restrict__ ao) {
    __shared__ float Ks[16][64];
    __shared__ float Vs[16][64];
    int qt = blockIdx.x;         // 0..32
    int hh = blockIdx.y;         // 0..7
    int b  = blockIdx.z;         // 0..1
    int tid = threadIdx.x;
    int ql = tid >> 2, dq = tid & 3;
    int i = qt * 64 + ql;
    const float* qrow = qh + ((size_t)b * T_ + i) * 512 + hh * 64 + dq * 16;
    float q[16], o[16];
    *(float4*)&q[0]  = *(const float4*)&qrow[0];
    *(float4*)&q[4]  = *(const float4*)&qrow[4];
    *(float4*)&q[8]  = *(const float4*)&qrow[8];
    *(float4*)&q[12] = *(const float4*)&qrow[12];
#pragma unroll
    for (int d = 0; d < 16; ++d) { q[d] *= 0.125f; o[d] = 0.f; }
    float m = -1e30f, l = 0.f;
    int jstart = qt * 64 - (WIN_ - 1);
    if (jstart < 0) jstart = 0;
    jstart &= ~15;
    int jend = qt * 64 + 63;
    int lr = tid >> 4, lc = (tid & 15) << 2;
    for (int jb = jstart; jb <= jend; jb += 16) {
        int j = jb + lr;
        const float* kro = kh + ((size_t)b * T_ + j) * 512 + hh * 64;
        const float* vro = vh + ((size_t)b * T_ + j) * 512 + hh * 64;
        __syncthreads();
        *(float4*)&Ks[lr][lc] = *(const float4*)&kro[lc];
        *(float4*)&Vs[lr][lc] = *(const float4*)&vro[lc];
        __syncthreads();
#pragma unroll 4
        for (int kk = 0; kk < 16; ++kk) {
            const float* kr = &Ks[kk][dq * 16];
            float4 k0 = *(const float4*)&kr[0];
            float4 k1 = *(const float4*)&kr[4];
            float4 k2 = *(const float4*)&kr[8];
            float4 k3 = *(const float4*)&kr[12];
            float s0 = fmaf(q[0],k0.x, fmaf(q[1],k0.y, fmaf(q[2],k0.z, q[3]*k0.w)));
            float s1 = fmaf(q[4],k1.x, fmaf(q[5],k1.y, fmaf(q[6],k1.z, q[7]*k1.w)));
            float s2 = fmaf(q[8],k2.x, fmaf(q[9],k2.y, fmaf(q[10],k2.z, q[11]*k2.w)));
            float s3 = fmaf(q[12],k3.x, fmaf(q[13],k3.y, fmaf(q[14],k3.z, q[15]*k3.w)));
            float sp = (s0 + s1) + (s2 + s3);
            sp += __shfl_xor(sp, 1);
            sp += __shfl_xor(sp, 2);
            int j2 = jb + kk;
            if ((j2 <= i) && (i - j2 < WIN_)) {
                float mn = fmaxf(m, sp);
                float al = __expf(m - mn);
                float p  = __expf(sp - mn);
                l = l * al + p;
                const float* vr = &Vs[kk][dq * 16];
                float4 v0 = *(const float4*)&vr[0];
                float4 v1 = *(const float4*)&vr[4];
                float4 v2 = *(const float4*)&vr[8];
                float4 v3 = *(const float4*)&vr[12];
                o[0]=o[0]*al+p*v0.x;  o[1]=o[1]*al+p*v0.y;  o[2]=o[2]*al+p*v0.z;  o[3]=o[3]*al+p*v0.w;
                o[4]=o[4]*al+p*v1.x;  o[5]=o[5]*al+p*v1.y;  o[6]=o[6]*al+p*v1.z;  o[7]=o[7]*al+p*v1.w;
                o[8]=o[8]*al+p*v2.x;  o[9]=o[9]*al+p*v2.y;  o[10]=o[10]*al+p*v2.z; o[11]=o[11]*al+p*v2.w;
                o[12]=o[12]*al+p*v3.x; o[13]=o[13]*al+p*v3.y; o[14]=o[14]*al+p*v3.z; o[15]=o[15]*al+p*v3.w;
                m = mn;
            }
        }
    }
    float inv = 1.0f / l;
#pragma unroll
    for (int d = 0; d < 16; ++d) o[d] *= inv;
    float* orow = ao + ((size_t)b * T_ + i) * 512 + hh * 64 + dq * 16;
    *(float4*)&orow[0]  = *(const float4*)&o[0];
    *(float4*)&orow[4]  = *(const float4*)&o[4];
    *(float4*)&orow[8]  = *(const float4*)&o[8];
    *(float4*)&orow[12] = *(const float4*)&o[12];
}

extern "C" void kernel_launch(void* const* d_in, const int* in_sizes, int n_in,
                              void* d_out, int out_size, void* d_ws, size_t ws_size,
                              hipStream_t stream) {
    (void)in_sizes; (void)n_in; (void)out_size; (void)ws_size;
    const float* x      = (const float*)d_in[0];
    const float* meta   = (const float*)d_in[1];
    const float* lmm_w  = (const float*)d_in[2];
    const float* w_q    = (const float*)d_in[3];
    const float* w_k    = (const float*)d_in[4];
    const float* w_v    = (const float*)d_in[5];
    const float* w_lr   = (const float*)d_in[6];
    const float* swa_wq = (const float*)d_in[7];
    const float* swa_wk = (const float*)d_in[8];
    const float* swa_wv = (const float*)d_in[9];
    const float* swa_wo = (const float*)d_in[10];
    float* out = (float*)d_out;
    float* ws  = (float*)d_ws;

    const size_t BTD = (size_t)BT_ * D_;       // 2162688
    float* b0 = ws + 0 * BTD;                  // xm  -> qh
    float* b1 = ws + 1 * BTD;                  // qq
    float* b2 = ws + 2 * BTD;                  // kk  -> scratch
    float* b3 = ws + 3 * BTD;                  // vv  -> h1q -> ao
    float* b4 = ws + 4 * BTD;                  // z0/dz0 -> r
    float* b5 = ws + 5 * BTD;                  // h1  -> kh
    float* b6 = ws + 6 * BTD;                  // z1/dz1 -> vh
    float* b7 = ws + 7 * BTD;                  // dp/dh1
    float* alr = ws + 8 * BTD;                 // BT_
    float* dWp = alr + BT_;                    // 16 * 262144 (layer-major: [2][8][512*512])
    float* Wn  = dWp + 16 * 262144;            // 2 * 262144

    dim3 blk(256);
    dim3 gEw(2112);        // BT_*128 / 256 float4-elements
    dim3 gg(66, 8);        // 4224/64 x 512/64
    dim3 gtn(8, 8, 8);

    build_xm_kernel<<<gEw, blk, 0, stream>>>(x, meta, b0);
    alr_kernel<<<dim3(1056), blk, 0, stream>>>(b0, w_lr, alr);
    gemm512<0,0><<<gg, blk, 0, stream>>>(b0, w_q, b1, nullptr, nullptr);              // qq
    gemm512<0,0><<<gg, blk, 0, stream>>>(b0, w_k, b2, nullptr, nullptr);              // kk
    gemm512<0,0><<<gg, blk, 0, stream>>>(b0, w_v, b3, nullptr, nullptr);              // vv
    gemm512<0,1><<<gg, blk, 0, stream>>>(b2, lmm_w, b5, b2, b4);                      // z0=b4, h1=b5
    gemm512<0,0><<<gg, blk, 0, stream>>>(b5, lmm_w + 262144, b6, nullptr, nullptr);   // z1=b6
    dpdz1_kernel<<<gEw, blk, 0, stream>>>(b5, b6, b3, alr, b7);                       // dp=b7, dz1=b6
    gemm512<1,2><<<gg, blk, 0, stream>>>(b6, lmm_w + 262144, b7, b7, nullptr);        // dh1=b7 (in-place)
    gemm_tn<<<gtn, blk, 0, stream>>>(b6, b5, dWp + 8 * 262144);                       // dW1 partials
    dz0_kernel<<<gEw, blk, 0, stream>>>(b7, b4);                                      // dz0=b4 (in-place)
    gemm_tn<<<gtn, blk, 0, stream>>>(b4, b2, dWp);                                    // dW0 partials
    adam_kernel<<<dim3(2048), blk, 0, stream>>>(lmm_w, dWp, Wn);                      // Wn
    gemm512<0,1><<<gg, blk, 0, stream>>>(b1, Wn, b3, b1, nullptr);                    // h1q=b3
    gemm512<0,1><<<gg, blk, 0, stream>>>(b3, Wn + 262144, b4, b3, nullptr);           // r=b4
    gemm512<0,0><<<gg, blk, 0, stream>>>(b4, swa_wq, b0, nullptr, nullptr);           // qh=b0
    gemm512<0,0><<<gg, blk, 0, stream>>>(b4, swa_wk, b5, nullptr, nullptr);           // kh=b5
    gemm512<0,0><<<gg, blk, 0, stream>>>(b4, swa_wv, b6, nullptr, nullptr);           // vh=b6
    swa_kernel<<<dim3(33, 8, 2), blk, 0, stream>>>(b0, b5, b6, b3);                   // ao=b3
    gemm512<0,3><<<gg, blk, 0, stream>>>(b3, swa_wo, out, nullptr, nullptr);          // out (drop meta rows)
}

// Round 2
// 547.198 us; speedup vs baseline: 1.5886x; 1.5886x over previous
//
#include <hip/hip_runtime.h>
#include <hip/hip_bf16.h>

#define B_   2
#define S_   2048
#define D_   512
#define M_   64
#define T_   2112
#define BT_  4224
#define H_   8
#define WIN_ 512

typedef short s16x8 __attribute__((ext_vector_type(8)));
typedef float f32x4 __attribute__((ext_vector_type(4)));
typedef unsigned short ushort_t;

__device__ __forceinline__ float siluf(float x) {
    float s = 1.0f / (1.0f + expf(-x));
    return x * s;
}
__device__ __forceinline__ float dsiluf(float x) {
    float s = 1.0f / (1.0f + expf(-x));
    return s * (1.0f + x * (1.0f - s));
}
__device__ __forceinline__ float bf2f(ushort_t u) {
    union { float f; unsigned int i; } x; x.i = ((unsigned int)u) << 16; return x.f;
}
__device__ __forceinline__ ushort_t f2bf(float f) {
    union { float f; unsigned int i; } x; x.f = f;
    unsigned int r = x.i + 0x7FFFu + ((x.i >> 16) & 1u);
    return (ushort_t)(r >> 16);
}
__device__ __forceinline__ void pack8(ushort_t* dst, const float* v) {
    ushort_t tmp[8];
#pragma unroll
    for (int i = 0; i < 8; ++i) tmp[i] = f2bf(v[i]);
    *(int4*)dst = *(const int4*)tmp;
}

// ---------------- build xm_bf = concat(meta, x) in bf16 ----------------
__global__ void build_xm_kernel(const float* __restrict__ x, const float* __restrict__ meta,
                                ushort_t* __restrict__ xmb) {
    int idx = blockIdx.x * 256 + threadIdx.x;   // 8-elem groups over BT_*64
    int seg = idx & 63;
    int row = idx >> 6;
    int b   = row / T_;
    int t   = row - b * T_;
    const float* src;
    if (t < M_) src = meta + (size_t)t * 512 + seg * 8;
    else        src = x + ((size_t)b * S_ + (t - M_)) * 512 + seg * 8;
    float v[8];
    *(float4*)&v[0] = *(const float4*)src;
    *(float4*)&v[4] = *(const float4*)(src + 4);
    pack8(xmb + (size_t)row * 512 + seg * 8, v);
}

// ---------------- weight converts ----------------
struct W8 { const float* s[8]; ushort_t* d[8]; };
__global__ void cvt_w_kernel(W8 p) {
    int w = blockIdx.y;
    int idx = blockIdx.x * 256 + threadIdx.x;   // 8 elems each, 128 blocks -> 262144
    const float* src = p.s[w] + (size_t)idx * 8;
    float v[8];
    *(float4*)&v[0] = *(const float4*)src;
    *(float4*)&v[4] = *(const float4*)(src + 4);
    pack8(p.d[w] + (size_t)idx * 8, v);
}
// transposed bf16 copy: dst[m][n] = src[n][m]  (512x512)
__global__ void cvt_wT_kernel(const float* __restrict__ src, ushort_t* __restrict__ dst) {
    __shared__ float t[32][33];
    int tid = threadIdx.x;
    int tr = tid >> 3, tc = (tid & 7) * 4;
    int r0 = blockIdx.y * 32, c0 = blockIdx.x * 32;
    *(float4*)&t[tr][tc] = *(const float4*)&src[(size_t)(r0 + tr) * 512 + c0 + tc];
    __syncthreads();
    ushort_t o[4];
#pragma unroll
    for (int i = 0; i < 4; ++i) o[i] = f2bf(t[tc + i][tr]);
    *(ushort2*)&dst[(size_t)(c0 + tr) * 512 + r0 + tc] =
        *(ushort2*)&o[0];
    *(ushort2*)&dst[(size_t)(c0 + tr) * 512 + r0 + tc + 2] =
        *(ushort2*)&o[2];
}

// ---------------- alr = sigmoid(xm @ w_lr^T) * 0.01 ----------------
__global__ void alr_kernel(const ushort_t* __restrict__ xmb, const float* __restrict__ wlr,
                           float* __restrict__ alr) {
    int r = blockIdx.x * 4 + (threadIdx.x >> 6);
    int lane = threadIdx.x & 63;
    const ushort_t* row = xmb + (size_t)r * D_;
    float s = 0.f;
#pragma unroll
    for (int k = 0; k < 8; ++k) s = fmaf(bf2f(row[lane + k * 64]), wlr[lane + k * 64], s);
#pragma unroll
    for (int off = 32; off >= 1; off >>= 1) s += __shfl_xor(s, off, 64);
    if (lane == 0) alr[r] = 0.01f / (1.0f + expf(-s));
}

// ---------------- bf16 MFMA GEMM: C[4224,512] = A_bf @ Bt_bf^T  (Bt is [n][k]) ----------------
// RES: 0 none; 1 out = Rf + silu(acc); 2 out = bf2f(Rb) + silu(acc); 3 out = Rf + acc
// WF32 / WBF: write fp32 C / bf16 Cb.  WZ: also write raw acc to Z (fp32).
template<int RES, int WF32, int WBF, int WZ>
__global__ __launch_bounds__(256)
void mgemm(const ushort_t* __restrict__ A, const ushort_t* __restrict__ Bt,
           float* __restrict__ C, ushort_t* __restrict__ Cb,
           const float* __restrict__ Rf, const ushort_t* __restrict__ Rb,
           float* __restrict__ Z) {
    __shared__ ushort_t As[64 * 64];
    __shared__ ushort_t Bs[64 * 64];
    int tid = threadIdx.x;
    int m0 = blockIdx.x * 64, n0 = blockIdx.y * 64;
    int srow = tid >> 2;             // 0..63
    int sseg = (tid & 3) << 1;       // 0,2,4,6 (8-bf16 segments)
    int wid = tid >> 6;
    int lane = tid & 63;
    int wm = (wid & 1) << 5;         // 0/32
    int wn = (wid >> 1) << 5;        // 0/32
    int fr = lane & 15;
    int fq = lane >> 4;              // quad
    f32x4 acc[2][2] = {};
    for (int k0 = 0; k0 < 512; k0 += 64) {
        const ushort_t* ga = A  + (size_t)(m0 + srow) * 512 + k0 + sseg * 8;
        const ushort_t* gb = Bt + (size_t)(n0 + srow) * 512 + k0 + sseg * 8;
        int4 av0 = *(const int4*)ga;
        int4 av1 = *(const int4*)(ga + 8);
        int4 bv0 = *(const int4*)gb;
        int4 bv1 = *(const int4*)(gb + 8);
        __syncthreads();
        int sw = srow & 7;
        *(int4*)&As[srow * 64 + ((sseg    ) ^ sw) * 8] = av0;
        *(int4*)&As[srow * 64 + ((sseg + 1) ^ sw) * 8] = av1;
        *(int4*)&Bs[srow * 64 + ((sseg    ) ^ sw) * 8] = bv0;
        *(int4*)&Bs[srow * 64 + ((sseg + 1) ^ sw) * 8] = bv1;
        __syncthreads();
#pragma unroll
        for (int ks = 0; ks < 2; ++ks) {
            int seg = fq + ks * 4;
            int rA0 = wm + fr,      rA1 = wm + 16 + fr;
            int rB0 = wn + fr,      rB1 = wn + 16 + fr;
            s16x8 a0 = *(const s16x8*)&As[rA0 * 64 + (seg ^ (rA0 & 7)) * 8];
            s16x8 a1 = *(const s16x8*)&As[rA1 * 64 + (seg ^ (rA1 & 7)) * 8];
            s16x8 b0 = *(const s16x8*)&Bs[rB0 * 64 + (seg ^ (rB0 & 7)) * 8];
            s16x8 b1 = *(const s16x8*)&Bs[rB1 * 64 + (seg ^ (rB1 & 7)) * 8];
            acc[0][0] = __builtin_amdgcn_mfma_f32_16x16x32_bf16(a0, b0, acc[0][0], 0, 0, 0);
            acc[0][1] = __builtin_amdgcn_mfma_f32_16x16x32_bf16(a0, b1, acc[0][1], 0, 0, 0);
            acc[1][0] = __builtin_amdgcn_mfma_f32_16x16x32_bf16(a1, b0, acc[1][0], 0, 0, 0);
            acc[1][1] = __builtin_amdgcn_mfma_f32_16x16x32_bf16(a1, b1, acc[1][1], 0, 0, 0);
        }
    }
#pragma unroll
    for (int i = 0; i < 2; ++i) {
#pragma unroll
        for (int j = 0; j < 2; ++j) {
#pragma unroll
            for (int r = 0; r < 4; ++r) {
                int row = m0 + wm + i * 16 + fq * 4 + r;
                int col = n0 + wn + j * 16 + fr;
                size_t off = (size_t)row * 512 + col;
                float v = acc[i][j][r];
                if (WZ) Z[off] = v;
                if (RES == 1) v = Rf[off] + siluf(v);
                if (RES == 2) v = bf2f(Rb[off]) + siluf(v);
                if (RES == 3) v = Rf[off] + v;
                if (WF32) C[off] = v;
                if (WBF)  Cb[off] = f2bf(v);
            }
        }
    }
}

// ---------------- TN GEMM for dW (fp32): C[512,512] = sum_t A[t,m]*B[t,n], 4 split-K slices ----------------
__global__ __launch_bounds__(256)
void gemm_tn(const float* __restrict__ A, const float* __restrict__ Bm, float* __restrict__ Cpart) {
    __shared__ float As[16][68];
    __shared__ float Bs[16][68];
    int tid = threadIdx.x;
    int m0 = blockIdx.x * 64, n0 = blockIdx.y * 64;
    int kbase = blockIdx.z * 1056;
    int lr = tid >> 4, lc = (tid & 15) << 2;
    int tm = (tid & 15) << 2, tn = (tid >> 4) << 2;
    float acc[4][4] = {};
    for (int kt = 0; kt < 66; ++kt) {
        int k0 = kbase + kt * 16;
        float4 av = *(const float4*)&A[(size_t)(k0 + lr) * 512 + m0 + lc];
        float4 bv = *(const float4*)&Bm[(size_t)(k0 + lr) * 512 + n0 + lc];
        __syncthreads();
        *(float4*)&As[lr][lc] = av;
        *(float4*)&Bs[lr][lc] = bv;
        __syncthreads();
#pragma unroll
        for (int kk = 0; kk < 16; ++kk) {
            float4 a = *(const float4*)&As[kk][tm];
            float4 b = *(const float4*)&Bs[kk][tn];
            acc[0][0] = fmaf(a.x,b.x,acc[0][0]); acc[0][1] = fmaf(a.x,b.y,acc[0][1]);
            acc[0][2] = fmaf(a.x,b.z,acc[0][2]); acc[0][3] = fmaf(a.x,b.w,acc[0][3]);
            acc[1][0] = fmaf(a.y,b.x,acc[1][0]); acc[1][1] = fmaf(a.y,b.y,acc[1][1]);
            acc[1][2] = fmaf(a.y,b.z,acc[1][2]); acc[1][3] = fmaf(a.y,b.w,acc[1][3]);
            acc[2][0] = fmaf(a.z,b.x,acc[2][0]); acc[2][1] = fmaf(a.z,b.y,acc[2][1]);
            acc[2][2] = fmaf(a.z,b.z,acc[2][2]); acc[2][3] = fmaf(a.z,b.w,acc[2][3]);
            acc[3][0] = fmaf(a.w,b.x,acc[3][0]); acc[3][1] = fmaf(a.w,b.y,acc[3][1]);
            acc[3][2] = fmaf(a.w,b.z,acc[3][2]); acc[3][3] = fmaf(a.w,b.w,acc[3][3]);
        }
    }
    float* C = Cpart + (size_t)blockIdx.z * 262144;
#pragma unroll
    for (int i = 0; i < 4; ++i) {
        float4 o; o.x = acc[i][0]; o.y = acc[i][1]; o.z = acc[i][2]; o.w = acc[i][3];
        *(float4*)&C[(size_t)(m0 + tm + i) * 512 + n0 + tn] = o;
    }
}

// ---------------- dp = (2*alr/D)*(h1 + silu(z1) - v); dz1 = dp*silu'(z1) (fp32 over z1 + bf16) ----------------
__global__ void dpdz1_kernel(const float* __restrict__ h1, float* __restrict__ z1,
                             const ushort_t* __restrict__ vvb, const float* __restrict__ alr,
                             float* __restrict__ dp, ushort_t* __restrict__ dz1b) {
    int idx = blockIdx.x * 256 + threadIdx.x;   // 8-elem groups
    int r = idx >> 6;
    float c = (2.0f / 512.0f) * alr[r];
    float z[8], h[8], dpv[8], dzv[8];
    *(float4*)&z[0] = ((const float4*)z1)[idx * 2];
    *(float4*)&z[4] = ((const float4*)z1)[idx * 2 + 1];
    *(float4*)&h[0] = ((const float4*)h1)[idx * 2];
    *(float4*)&h[4] = ((const float4*)h1)[idx * 2 + 1];
    int4 vb = ((const int4*)vvb)[idx];
    const ushort_t* vu = (const ushort_t*)&vb;
#pragma unroll
    for (int i = 0; i < 8; ++i) {
        float zz = z[i];
        float s = 1.f / (1.f + expf(-zz));
        float d = c * (h[i] + zz * s - bf2f(vu[i]));
        dpv[i] = d;
        dzv[i] = d * (s * (1.f + zz * (1.f - s)));
    }
    ((float4*)dp)[idx * 2]     = *(float4*)&dpv[0];
    ((float4*)dp)[idx * 2 + 1] = *(float4*)&dpv[4];
    ((float4*)z1)[idx * 2]     = *(float4*)&dzv[0];
    ((float4*)z1)[idx * 2 + 1] = *(float4*)&dzv[4];
    pack8(dz1b + (size_t)idx * 8, dzv);
}

// ---------------- dz0 = dh1 * silu'(z0) (in-place over z0, fp32) ----------------
__global__ void dz0_kernel(const float* __restrict__ dh1, float* __restrict__ z0) {
    int idx = blockIdx.x * 256 + threadIdx.x;
    float4 z4 = ((const float4*)z0)[idx];
    float4 g4 = ((const float4*)dh1)[idx];
    float4 o;
    o.x = g4.x * dsiluf(z4.x); o.y = g4.y * dsiluf(z4.y);
    o.z = g4.z * dsiluf(z4.z); o.w = g4.w * dsiluf(z4.w);
    ((float4*)z0)[idx] = o;
}

// ---------------- AdamW first step (4 partial slices), writes fp32 + bf16 ----------------
__global__ void adam_kernel(const float* __restrict__ W, const float* __restrict__ dWp,
                            float* __restrict__ Wn, ushort_t* __restrict__ Wnb) {
    int idx = blockIdx.x * 256 + threadIdx.x;   // 0..524287
    int layer = idx >> 18;
    int i = idx & 262143;
    const float* base = dWp + (size_t)layer * 4 * 262144 + i;
    float g = 0.f;
#pragma unroll
    for (int z = 0; z < 4; ++z) g += base[(size_t)z * 262144];
    g *= (1.0f / 16.0f);
    float w = W[idx];
    float o = w * (1.0f - 1e-5f) - 1e-3f * g / (fabsf(g) + 1e-8f);
    Wn[idx] = o;
    Wnb[idx] = f2bf(o);
}

// ---------------- sliding-window attention (fp32, tile-hoisted online softmax) ----------------
__global__ __launch_bounds__(256)
void swa_kernel(const float* __restrict__ qh, const float* __restrict__ kh,
                const float* __restrict__ vh, float* __restrict__ ao) {
    __shared__ float Ks[16][64];
    __shared__ float Vs[16][64];
    int qt = (int)(gridDim.x - 1) - (int)blockIdx.x;   // longest blocks first
    int hh = blockIdx.y;
    int b  = blockIdx.z;
    int tid = threadIdx.x;
    int ql = tid >> 2, dq = tid & 3;
    int i = qt * 64 + ql;
    const float* qrow = qh + ((size_t)b * T_ + i) * 512 + hh * 64 + dq * 16;
    float q[16], o[16];
    *(float4*)&q[0]  = *(const float4*)&qrow[0];
    *(float4*)&q[4]  = *(const float4*)&qrow[4];
    *(float4*)&q[8]  = *(const float4*)&qrow[8];
    *(float4*)&q[12] = *(const float4*)&qrow[12];
#pragma unroll
    for (int d = 0; d < 16; ++d) { q[d] *= 0.125f; o[d] = 0.f; }
    float m = -1e30f, l = 0.f;
    int jstart = qt * 64 - (WIN_ - 1);
    if (jstart < 0) jstart = 0;
    jstart &= ~15;
    int jend = qt * 64 + 63;
    int lr = tid >> 4, lc = (tid & 15) << 2;
    for (int jb = jstart; jb <= jend; jb += 16) {
        int j = jb + lr;
        const float* kro = kh + ((size_t)b * T_ + j) * 512 + hh * 64;
        const float* vro = vh + ((size_t)b * T_ + j) * 512 + hh * 64;
        __syncthreads();
        *(float4*)&Ks[lr][lc] = *(const float4*)&kro[lc];
        *(float4*)&Vs[lr][lc] = *(const float4*)&vro[lc];
        __syncthreads();
        float s[16];
        float tmax = -1e30f;
#pragma unroll
        for (int kk = 0; kk < 16; ++kk) {
            const float* kr = &Ks[kk][dq * 16];
            float4 k0 = *(const float4*)&kr[0];
            float4 k1 = *(const float4*)&kr[4];
            float4 k2 = *(const float4*)&kr[8];
            float4 k3 = *(const float4*)&kr[12];
            float s0 = fmaf(q[0],k0.x, fmaf(q[1],k0.y, fmaf(q[2],k0.z, q[3]*k0.w)));
            float s1 = fmaf(q[4],k1.x, fmaf(q[5],k1.y, fmaf(q[6],k1.z, q[7]*k1.w)));
            float s2 = fmaf(q[8],k2.x, fmaf(q[9],k2.y, fmaf(q[10],k2.z, q[11]*k2.w)));
            float s3 = fmaf(q[12],k3.x, fmaf(q[13],k3.y, fmaf(q[14],k3.z, q[15]*k3.w)));
            float sp = (s0 + s1) + (s2 + s3);
            sp += __shfl_xor(sp, 1);
            sp += __shfl_xor(sp, 2);
            int j2 = jb + kk;
            bool valid = (j2 <= i) && (i - j2 < WIN_);
            sp = valid ? sp : -1e30f;
            s[kk] = sp;
            tmax = fmaxf(tmax, sp);
        }
        float mn = fmaxf(m, tmax);
        float al = __expf(m - mn);
        m = mn;
        l *= al;
#pragma unroll
        for (int d = 0; d < 16; ++d) o[d] *= al;
#pragma unroll
        for (int kk = 0; kk < 16; ++kk) {
            float p = (s[kk] > -1e29f) ? __expf(s[kk] - mn) : 0.f;
            l += p;
            const float* vr = &Vs[kk][dq * 16];
            float4 v0 = *(const float4*)&vr[0];
            float4 v1 = *(const float4*)&vr[4];
            float4 v2 = *(const float4*)&vr[8];
            float4 v3 = *(const float4*)&vr[12];
            o[0]=fmaf(p,v0.x,o[0]);  o[1]=fmaf(p,v0.y,o[1]);  o[2]=fmaf(p,v0.z,o[2]);  o[3]=fmaf(p,v0.w,o[3]);
            o[4]=fmaf(p,v1.x,o[4]);  o[5]=fmaf(p,v1.y,o[5]);  o[6]=fmaf(p,v1.z,o[6]);  o[7]=fmaf(p,v1.w,o[7]);
            o[8]=fmaf(p,v2.x,o[8]);  o[9]=fmaf(p,v2.y,o[9]);  o[10]=fmaf(p,v2.z,o[10]); o[11]=fmaf(p,v2.w,o[11]);
            o[12]=fmaf(p,v3.x,o[12]); o[13]=fmaf(p,v3.y,o[13]); o[14]=fmaf(p,v3.z,o[14]); o[15]=fmaf(p,v3.w,o[15]);
        }
    }
    float inv = 1.0f / l;
#pragma unroll
    for (int d = 0; d < 16; ++d) o[d] *= inv;
    float* orow = ao + ((size_t)b * T_ + i) * 512 + hh * 64 + dq * 16;
    *(float4*)&orow[0]  = *(const float4*)&o[0];
    *(float4*)&orow[4]  = *(const float4*)&o[4];
    *(float4*)&orow[8]  = *(const float4*)&o[8];
    *(float4*)&orow[12] = *(const float4*)&o[12];
}

// ---------------- final fp32 GEMM: out = ao @ wo^T, drop meta rows ----------------
__global__ __launch_bounds__(256)
void gemm_wo(const float* __restrict__ A, const float* __restrict__ Bm, float* __restrict__ C) {
    __shared__ float As[16][68];
    __shared__ float Bs[16][68];
    int tid = threadIdx.x;
    int m0 = blockIdx.x * 64, n0 = blockIdx.y * 64;
    int alm = tid >> 2;
    int alk = (tid & 3) << 2;
    int tm = (tid & 15) << 2;
    int tn = (tid >> 4) << 2;
    float acc[4][4] = {};
    for (int k0 = 0; k0 < 512; k0 += 16) {
        float4 av = *(const float4*)&A[(size_t)(m0 + alm) * 512 + k0 + alk];
        float4 bv = *(const float4*)&Bm[(size_t)(n0 + alm) * 512 + k0 + alk];
        __syncthreads();
        As[alk + 0][alm] = av.x; As[alk + 1][alm] = av.y;
        As[alk + 2][alm] = av.z; As[alk + 3][alm] = av.w;
        Bs[alk + 0][alm] = bv.x; Bs[alk + 1][alm] = bv.y;
        Bs[alk + 2][alm] = bv.z; Bs[alk + 3][alm] = bv.w;
        __syncthreads();
#pragma unroll
        for (int kk = 0; kk < 16; ++kk) {
            float4 a = *(const float4*)&As[kk][tm];
            float4 b = *(const float4*)&Bs[kk][tn];
            acc[0][0] = fmaf(a.x,b.x,acc[0][0]); acc[0][1] = fmaf(a.x,b.y,acc[0][1]);
            acc[0][2] = fmaf(a.x,b.z,acc[0][2]); acc[0][3] = fmaf(a.x,b.w,acc[0][3]);
            acc[1][0] = fmaf(a.y,b.x,acc[1][0]); acc[1][1] = fmaf(a.y,b.y,acc[1][1]);
            acc[1][2] = fmaf(a.y,b.z,acc[1][2]); acc[1][3] = fmaf(a.y,b.w,acc[1][3]);
            acc[2][0] = fmaf(a.z,b.x,acc[2][0]); acc[2][1] = fmaf(a.z,b.y,acc[2][1]);
            acc[2][2] = fmaf(a.z,b.z,acc[2][2]); acc[2][3] = fmaf(a.z,b.w,acc[2][3]);
            acc[3][0] = fmaf(a.w,b.x,acc[3][0]); acc[3][1] = fmaf(a.w,b.y,acc[3][1]);
            acc[3][2] = fmaf(a.w,b.z,acc[3][2]); acc[3][3] = fmaf(a.w,b.w,acc[3][3]);
        }
    }
#pragma unroll
    for (int i = 0; i < 4; ++i) {
        int row = m0 + tm + i;
        int b = row / T_;
        int t = row - b * T_;
        if (t >= M_) {
            float4 o; o.x = acc[i][0]; o.y = acc[i][1]; o.z = acc[i][2]; o.w = acc[i][3];
            *(float4*)&C[((size_t)b * S_ + (t - M_)) * 512 + n0 + tn] = o;
        }
    }
}

extern "C" void kernel_launch(void* const* d_in, const int* in_sizes, int n_in,
                              void* d_out, int out_size, void* d_ws, size_t ws_size,
                              hipStream_t stream) {
    (void)in_sizes; (void)n_in; (void)out_size; (void)ws_size;
    const float* x      = (const float*)d_in[0];
    const float* meta   = (const float*)d_in[1];
    const float* lmm_w  = (const float*)d_in[2];
    const float* w_q    = (const float*)d_in[3];
    const float* w_k    = (const float*)d_in[4];
    const float* w_v    = (const float*)d_in[5];
    const float* w_lr   = (const float*)d_in[6];
    const float* swa_wq = (const float*)d_in[7];
    const float* swa_wk = (const float*)d_in[8];
    const float* swa_wv = (const float*)d_in[9];
    const float* swa_wo = (const float*)d_in[10];
    float* out = (float*)d_out;
    float* ws  = (float*)d_ws;

    const size_t BTD = (size_t)BT_ * D_;       // 2162688
    // fp32 buffers (5 x BTD)
    float* b2 = ws + 0 * BTD;                  // kk
    float* b4 = ws + 1 * BTD;                  // z0/dz0 -> ao
    float* b5 = ws + 2 * BTD;                  // h1 -> kh
    float* b6 = ws + 3 * BTD;                  // z1/dz1 -> vh
    float* b7 = ws + 4 * BTD;                  // dp/dh1 -> qh
    float* alr = ws + 5 * BTD;                 // BT_
    float* dWp = alr + BT_;                    // [2][4][262144] = 2,097,152 floats
    float* Wn  = dWp + 2 * 4 * 262144;         // 524288 floats
    // bf16 region (ushort), 16B-aligned
    ushort_t* xb = (ushort_t*)(Wn + 524288);
    ushort_t* xm_bf  = xb + 0 * BTD;           // -> reused as r_bf
    ushort_t* qq_bf  = xb + 1 * BTD;
    ushort_t* kk_bf  = xb + 2 * BTD;           // -> reused as h1q_bf
    ushort_t* vv_bf  = xb + 3 * BTD;
    ushort_t* h1_bf  = xb + 4 * BTD;
    ushort_t* dz1_bf = xb + 5 * BTD;
    ushort_t* r_bf   = xm_bf;
    ushort_t* h1q_bf = kk_bf;
    ushort_t* wbf = xb + 6 * BTD;              // 9 x 262144 weights + Wn_bf 2 x 262144
    ushort_t* wq_bf  = wbf + 0 * 262144;
    ushort_t* wk_bf  = wbf + 1 * 262144;
    ushort_t* wv_bf  = wbf + 2 * 262144;
    ushort_t* l0_bf  = wbf + 3 * 262144;
    ushort_t* l1_bf  = wbf + 4 * 262144;
    ushort_t* sq_bf  = wbf + 5 * 262144;
    ushort_t* sk_bf  = wbf + 6 * 262144;
    ushort_t* sv_bf  = wbf + 7 * 262144;
    ushort_t* l1t_bf = wbf + 8 * 262144;
    ushort_t* wn_bf  = wbf + 9 * 262144;

    dim3 blk(256);
    dim3 g8(1056);         // BT_*512/8/256
    dim3 gg(66, 8);
    dim3 gtn(8, 8, 4);

    W8 wl;
    wl.s[0] = w_q;    wl.d[0] = wq_bf;
    wl.s[1] = w_k;    wl.d[1] = wk_bf;
    wl.s[2] = w_v;    wl.d[2] = wv_bf;
    wl.s[3] = lmm_w;  wl.d[3] = l0_bf;
    wl.s[4] = lmm_w + 262144; wl.d[4] = l1_bf;
    wl.s[5] = swa_wq; wl.d[5] = sq_bf;
    wl.s[6] = swa_wk; wl.d[6] = sk_bf;
    wl.s[7] = swa_wv; wl.d[7] = sv_bf;

    cvt_w_kernel<<<dim3(128, 8), blk, 0, stream>>>(wl);
    cvt_wT_kernel<<<dim3(16, 16), blk, 0, stream>>>(lmm_w + 262144, l1t_bf);
    build_xm_kernel<<<g8, blk, 0, stream>>>(x, meta, xm_bf);
    alr_kernel<<<dim3(1056), blk, 0, stream>>>(xm_bf, w_lr, alr);
    mgemm<0,0,1,0><<<gg, blk, 0, stream>>>(xm_bf, wq_bf, nullptr, qq_bf, nullptr, nullptr, nullptr);  // qq_bf
    mgemm<0,1,1,0><<<gg, blk, 0, stream>>>(xm_bf, wk_bf, b2, kk_bf, nullptr, nullptr, nullptr);       // kk
    mgemm<0,0,1,0><<<gg, blk, 0, stream>>>(xm_bf, wv_bf, nullptr, vv_bf, nullptr, nullptr, nullptr);  // vv_bf
    mgemm<1,1,1,1><<<gg, blk, 0, stream>>>(kk_bf, l0_bf, b5, h1_bf, b2, nullptr, b4);                 // h1=b5, z0=b4
    mgemm<0,1,0,0><<<gg, blk, 0, stream>>>(h1_bf, l1_bf, b6, nullptr, nullptr, nullptr, nullptr);     // z1=b6
    dpdz1_kernel<<<g8, blk, 0, stream>>>(b5, b6, vv_bf, alr, b7, dz1_bf);                             // dp=b7, dz1=b6
    mgemm<3,1,0,0><<<gg, blk, 0, stream>>>(dz1_bf, l1t_bf, b7, nullptr, b7, nullptr, nullptr);        // dh1=b7
    gemm_tn<<<gtn, blk, 0, stream>>>(b6, b5, dWp + 4 * 262144);                                       // dW1
    dz0_kernel<<<dim3(2112), blk, 0, stream>>>(b7, b4);                                               // dz0=b4
    gemm_tn<<<gtn, blk, 0, stream>>>(b4, b2, dWp);                                                    // dW0
    adam_kernel<<<dim3(2048), blk, 0, stream>>>(lmm_w, dWp, Wn, wn_bf);                               // Wn
    mgemm<2,0,1,0><<<gg, blk, 0, stream>>>(qq_bf, wn_bf, nullptr, h1q_bf, nullptr, qq_bf, nullptr);   // h1q_bf
    mgemm<2,0,1,0><<<gg, blk, 0, stream>>>(h1q_bf, wn_bf + 262144, nullptr, r_bf, nullptr, h1q_bf, nullptr); // r_bf
    mgemm<0,1,0,0><<<gg, blk, 0, stream>>>(r_bf, sq_bf, b7, nullptr, nullptr, nullptr, nullptr);      // qh=b7
    mgemm<0,1,0,0><<<gg, blk, 0, stream>>>(r_bf, sk_bf, b5, nullptr, nullptr, nullptr, nullptr);      // kh=b5
    mgemm<0,1,0,0><<<gg, blk, 0, stream>>>(r_bf, sv_bf, b6, nullptr, nullptr, nullptr, nullptr);      // vh=b6
    swa_kernel<<<dim3(33, 8, 2), blk, 0, stream>>>(b7, b5, b6, b4);                                   // ao=b4
    gemm_wo<<<gg, blk, 0, stream>>>(b4, swa_wo, out);                                                 // out
}

// Round 3
// 301.246 us; speedup vs baseline: 2.8857x; 1.8164x over previous
//
#include <hip/hip_runtime.h>
#include <hip/hip_bf16.h>

#define B_   2
#define S_   2048
#define D_   512
#define M_   64
#define T_   2112
#define BT_  4224
#define H_   8
#define WIN_ 512

typedef short s16x8 __attribute__((ext_vector_type(8)));
typedef float f32x4 __attribute__((ext_vector_type(4)));
typedef unsigned short ushort_t;

__device__ __forceinline__ float siluf(float x) {
    float s = 1.0f / (1.0f + expf(-x));
    return x * s;
}
__device__ __forceinline__ float dsiluf(float x) {
    float s = 1.0f / (1.0f + expf(-x));
    return s * (1.0f + x * (1.0f - s));
}
__device__ __forceinline__ float bf2f(ushort_t u) {
    union { float f; unsigned int i; } x; x.i = ((unsigned int)u) << 16; return x.f;
}
__device__ __forceinline__ ushort_t f2bf(float f) {
    union { float f; unsigned int i; } x; x.f = f;
    unsigned int r = x.i + 0x7FFFu + ((x.i >> 16) & 1u);
    return (ushort_t)(r >> 16);
}
__device__ __forceinline__ void pack8(ushort_t* dst, const float* v) {
    ushort_t tmp[8];
#pragma unroll
    for (int i = 0; i < 8; ++i) tmp[i] = f2bf(v[i]);
    *(int4*)dst = *(const int4*)tmp;
}

// ---------------- build xm_bf = concat(meta, x) in bf16 ----------------
__global__ void build_xm_kernel(const float* __restrict__ x, const float* __restrict__ meta,
                                ushort_t* __restrict__ xmb) {
    int idx = blockIdx.x * 256 + threadIdx.x;   // 8-elem groups over BT_*64
    int seg = idx & 63;
    int row = idx >> 6;
    int b   = row / T_;
    int t   = row - b * T_;
    const float* src;
    if (t < M_) src = meta + (size_t)t * 512 + seg * 8;
    else        src = x + ((size_t)b * S_ + (t - M_)) * 512 + seg * 8;
    float v[8];
    *(float4*)&v[0] = *(const float4*)src;
    *(float4*)&v[4] = *(const float4*)(src + 4);
    pack8(xmb + (size_t)row * 512 + seg * 8, v);
}

// ---------------- weight converts ----------------
struct W8 { const float* s[8]; ushort_t* d[8]; };
__global__ void cvt_w_kernel(W8 p) {
    int w = blockIdx.y;
    int idx = blockIdx.x * 256 + threadIdx.x;
    const float* src = p.s[w] + (size_t)idx * 8;
    float v[8];
    *(float4*)&v[0] = *(const float4*)src;
    *(float4*)&v[4] = *(const float4*)(src + 4);
    pack8(p.d[w] + (size_t)idx * 8, v);
}
// transposed bf16 copy: dst[m][n] = src[n][m]  (512x512)
__global__ void cvt_wT_kernel(const float* __restrict__ src, ushort_t* __restrict__ dst) {
    __shared__ float t[32][33];
    int tid = threadIdx.x;
    int tr = tid >> 3, tc = (tid & 7) * 4;
    int r0 = blockIdx.y * 32, c0 = blockIdx.x * 32;
    *(float4*)&t[tr][tc] = *(const float4*)&src[(size_t)(r0 + tr) * 512 + c0 + tc];
    __syncthreads();
    ushort_t o[4];
#pragma unroll
    for (int i = 0; i < 4; ++i) o[i] = f2bf(t[tc + i][tr]);
    *(ushort2*)&dst[(size_t)(c0 + tr) * 512 + r0 + tc] = *(ushort2*)&o[0];
    *(ushort2*)&dst[(size_t)(c0 + tr) * 512 + r0 + tc + 2] = *(ushort2*)&o[2];
}

// ---------------- alr = sigmoid(xm @ w_lr^T) * 0.01 ----------------
__global__ void alr_kernel(const ushort_t* __restrict__ xmb, const float* __restrict__ wlr,
                           float* __restrict__ alr) {
    int r = blockIdx.x * 4 + (threadIdx.x >> 6);
    int lane = threadIdx.x & 63;
    const ushort_t* row = xmb + (size_t)r * D_;
    float s = 0.f;
#pragma unroll
    for (int k = 0; k < 8; ++k) s = fmaf(bf2f(row[lane + k * 64]), wlr[lane + k * 64], s);
#pragma unroll
    for (int off = 32; off >= 1; off >>= 1) s += __shfl_xor(s, off, 64);
    if (lane == 0) alr[r] = 0.01f / (1.0f + expf(-s));
}

// ---------------- bf16 MFMA GEMM: C[4224,512] = A_bf @ Bt_bf^T  (Bt is [n][k]) ----------------
// RES: 0 none; 1 out = Rf + silu(acc); 2 out = bf2f(Rb) + silu(acc); 3 out = Rf + acc
// WF32/WBF: fp32 / bf16 stores. WZ: raw acc to Z. WBT: bf16 transposed-per-batch store [b][col][t].
template<int RES, int WF32, int WBF, int WZ, int WBT>
__global__ __launch_bounds__(256)
void mgemm(const ushort_t* __restrict__ A, const ushort_t* __restrict__ Bt,
           float* __restrict__ C, ushort_t* __restrict__ Cb, ushort_t* __restrict__ CbT,
           const float* __restrict__ Rf, const ushort_t* __restrict__ Rb,
           float* __restrict__ Z) {
    __shared__ ushort_t As[64 * 64];
    __shared__ ushort_t Bs[64 * 64];
    int tid = threadIdx.x;
    int m0 = blockIdx.x * 64, n0 = blockIdx.y * 64;
    int srow = tid >> 2;
    int sseg = (tid & 3) << 1;
    int wid = tid >> 6;
    int lane = tid & 63;
    int wm = (wid & 1) << 5;
    int wn = (wid >> 1) << 5;
    int fr = lane & 15;
    int fq = lane >> 4;
    f32x4 acc[2][2] = {};
    for (int k0 = 0; k0 < 512; k0 += 64) {
        const ushort_t* ga = A  + (size_t)(m0 + srow) * 512 + k0 + sseg * 8;
        const ushort_t* gb = Bt + (size_t)(n0 + srow) * 512 + k0 + sseg * 8;
        int4 av0 = *(const int4*)ga;
        int4 av1 = *(const int4*)(ga + 8);
        int4 bv0 = *(const int4*)gb;
        int4 bv1 = *(const int4*)(gb + 8);
        __syncthreads();
        int sw = srow & 7;
        *(int4*)&As[srow * 64 + ((sseg    ) ^ sw) * 8] = av0;
        *(int4*)&As[srow * 64 + ((sseg + 1) ^ sw) * 8] = av1;
        *(int4*)&Bs[srow * 64 + ((sseg    ) ^ sw) * 8] = bv0;
        *(int4*)&Bs[srow * 64 + ((sseg + 1) ^ sw) * 8] = bv1;
        __syncthreads();
#pragma unroll
        for (int ks = 0; ks < 2; ++ks) {
            int seg = fq + ks * 4;
            int rA0 = wm + fr,      rA1 = wm + 16 + fr;
            int rB0 = wn + fr,      rB1 = wn + 16 + fr;
            s16x8 a0 = *(const s16x8*)&As[rA0 * 64 + (seg ^ (rA0 & 7)) * 8];
            s16x8 a1 = *(const s16x8*)&As[rA1 * 64 + (seg ^ (rA1 & 7)) * 8];
            s16x8 b0 = *(const s16x8*)&Bs[rB0 * 64 + (seg ^ (rB0 & 7)) * 8];
            s16x8 b1 = *(const s16x8*)&Bs[rB1 * 64 + (seg ^ (rB1 & 7)) * 8];
            acc[0][0] = __builtin_amdgcn_mfma_f32_16x16x32_bf16(a0, b0, acc[0][0], 0, 0, 0);
            acc[0][1] = __builtin_amdgcn_mfma_f32_16x16x32_bf16(a0, b1, acc[0][1], 0, 0, 0);
            acc[1][0] = __builtin_amdgcn_mfma_f32_16x16x32_bf16(a1, b0, acc[1][0], 0, 0, 0);
            acc[1][1] = __builtin_amdgcn_mfma_f32_16x16x32_bf16(a1, b1, acc[1][1], 0, 0, 0);
        }
    }
#pragma unroll
    for (int i = 0; i < 2; ++i) {
#pragma unroll
        for (int j = 0; j < 2; ++j) {
            int row0 = m0 + wm + i * 16 + fq * 4;
            int col  = n0 + wn + j * 16 + fr;
            float vv[4];
#pragma unroll
            for (int r = 0; r < 4; ++r) {
                size_t off = (size_t)(row0 + r) * 512 + col;
                float v = acc[i][j][r];
                if (WZ) Z[off] = v;
                if (RES == 1) v = Rf[off] + siluf(v);
                if (RES == 2) v = bf2f(Rb[off]) + siluf(v);
                if (RES == 3) v = Rf[off] + v;
                vv[r] = v;
                if (WF32) C[off] = v;
                if (WBF)  Cb[off] = f2bf(v);
            }
            if (WBT) {
                int bb = row0 / T_;
                int t0 = row0 - bb * T_;
                ushort_t t4[4];
#pragma unroll
                for (int r = 0; r < 4; ++r) t4[r] = f2bf(vv[r]);
                *(uint2*)&CbT[((size_t)(bb * 512) + col) * T_ + t0] = *(uint2*)t4;
            }
        }
    }
}

// ---------------- bf16 MFMA TN GEMM for dW: C[m][n] = sum_t A[t][m] B[t][n], split-K x6 ----------------
__global__ __launch_bounds__(256)
void gemm_tn_bf(const ushort_t* __restrict__ A, const ushort_t* __restrict__ Bm,
                float* __restrict__ Cpart) {
    __shared__ ushort_t At[64 * 64];
    __shared__ ushort_t Bt[64 * 64];
    int tid = threadIdx.x;
    int m0 = blockIdx.x * 64, n0 = blockIdx.y * 64;
    int kbase = blockIdx.z * 704;
    int wave = tid >> 6, lane = tid & 63;
    int fr = lane & 15, fq = lane >> 4;
    int wm = (wave & 1) << 5, wn = (wave >> 1) << 5;
    int tok = tid & 63, cs0 = tid >> 6;
    f32x4 acc[2][2] = {};
    for (int kt = 0; kt < 11; ++kt) {
        int t0 = kbase + kt * 64;
        int4 av[2], bv[2];
#pragma unroll
        for (int p = 0; p < 2; ++p) {
            int cs = cs0 + p * 4;
            av[p] = *(const int4*)&A[(size_t)(t0 + tok) * 512 + m0 + cs * 8];
            bv[p] = *(const int4*)&Bm[(size_t)(t0 + tok) * 512 + n0 + cs * 8];
        }
        __syncthreads();
#pragma unroll
        for (int p = 0; p < 2; ++p) {
            int cs = cs0 + p * 4;
            const ushort_t* au = (const ushort_t*)&av[p];
            const ushort_t* bu = (const ushort_t*)&bv[p];
#pragma unroll
            for (int j = 0; j < 8; ++j) {
                int row = cs * 8 + j;     // row&7 == j
                At[row * 64 + (((tok >> 3) ^ j) << 3) + (tok & 7)] = au[j];
                Bt[row * 64 + (((tok >> 3) ^ j) << 3) + (tok & 7)] = bu[j];
            }
        }
        __syncthreads();
#pragma unroll
        for (int ks = 0; ks < 2; ++ks) {
            int seg = ks * 4 + fq;
            s16x8 a0 = *(const s16x8*)&At[(wm + fr) * 64      + ((seg ^ (fr & 7)) << 3)];
            s16x8 a1 = *(const s16x8*)&At[(wm + 16 + fr) * 64 + ((seg ^ (fr & 7)) << 3)];
            s16x8 b0 = *(const s16x8*)&Bt[(wn + fr) * 64      + ((seg ^ (fr & 7)) << 3)];
            s16x8 b1 = *(const s16x8*)&Bt[(wn + 16 + fr) * 64 + ((seg ^ (fr & 7)) << 3)];
            acc[0][0] = __builtin_amdgcn_mfma_f32_16x16x32_bf16(a0, b0, acc[0][0], 0, 0, 0);
            acc[0][1] = __builtin_amdgcn_mfma_f32_16x16x32_bf16(a0, b1, acc[0][1], 0, 0, 0);
            acc[1][0] = __builtin_amdgcn_mfma_f32_16x16x32_bf16(a1, b0, acc[1][0], 0, 0, 0);
            acc[1][1] = __builtin_amdgcn_mfma_f32_16x16x32_bf16(a1, b1, acc[1][1], 0, 0, 0);
        }
    }
    float* C = Cpart + (size_t)blockIdx.z * 262144;
#pragma unroll
    for (int i = 0; i < 2; ++i)
#pragma unroll
        for (int j = 0; j < 2; ++j)
#pragma unroll
            for (int r = 0; r < 4; ++r)
                C[(size_t)(m0 + wm + i * 16 + fq * 4 + r) * 512 + n0 + wn + j * 16 + fr] =
                    acc[i][j][r];
}

// ---------------- dp = (2*alr/D)*(h1 + silu(z1) - v); dz1 = dp*silu'(z1) ----------------
__global__ void dpdz1_kernel(const float* __restrict__ h1, const float* __restrict__ z1,
                             const ushort_t* __restrict__ vvb, const float* __restrict__ alr,
                             float* __restrict__ dp, ushort_t* __restrict__ dz1b) {
    int idx = blockIdx.x * 256 + threadIdx.x;   // 8-elem groups
    int r = idx >> 6;
    float c = (2.0f / 512.0f) * alr[r];
    float z[8], h[8], dpv[8], dzv[8];
    *(float4*)&z[0] = ((const float4*)z1)[idx * 2];
    *(float4*)&z[4] = ((const float4*)z1)[idx * 2 + 1];
    *(float4*)&h[0] = ((const float4*)h1)[idx * 2];
    *(float4*)&h[4] = ((const float4*)h1)[idx * 2 + 1];
    int4 vb = ((const int4*)vvb)[idx];
    const ushort_t* vu = (const ushort_t*)&vb;
#pragma unroll
    for (int i = 0; i < 8; ++i) {
        float zz = z[i];
        float s = 1.f / (1.f + expf(-zz));
        float d = c * (h[i] + zz * s - bf2f(vu[i]));
        dpv[i] = d;
        dzv[i] = d * (s * (1.f + zz * (1.f - s)));
    }
    ((float4*)dp)[idx * 2]     = *(float4*)&dpv[0];
    ((float4*)dp)[idx * 2 + 1] = *(float4*)&dpv[4];
    pack8(dz1b + (size_t)idx * 8, dzv);
}

// ---------------- dz0 = dh1 * silu'(z0) -> bf16 ----------------
__global__ void dz0_kernel(const float* __restrict__ dh1, const float* __restrict__ z0,
                           ushort_t* __restrict__ dz0b) {
    int idx = blockIdx.x * 256 + threadIdx.x;   // 8-elem groups
    float z[8], g[8], o[8];
    *(float4*)&z[0] = ((const float4*)z0)[idx * 2];
    *(float4*)&z[4] = ((const float4*)z0)[idx * 2 + 1];
    *(float4*)&g[0] = ((const float4*)dh1)[idx * 2];
    *(float4*)&g[4] = ((const float4*)dh1)[idx * 2 + 1];
#pragma unroll
    for (int i = 0; i < 8; ++i) o[i] = g[i] * dsiluf(z[i]);
    pack8(dz0b + (size_t)idx * 8, o);
}

// ---------------- AdamW first step (6 partial slices) -> bf16 weights ----------------
__global__ void adam_kernel(const float* __restrict__ W, const float* __restrict__ dWp,
                            ushort_t* __restrict__ Wnb) {
    int idx = blockIdx.x * 256 + threadIdx.x;   // 0..524287
    int layer = idx >> 18;
    int i = idx & 262143;
    const float* base = dWp + (size_t)layer * 6 * 262144 + i;
    float g = 0.f;
#pragma unroll
    for (int z = 0; z < 6; ++z) g += base[(size_t)z * 262144];
    g *= (1.0f / 16.0f);
    float w = W[idx];
    float o = w * (1.0f - 1e-5f) - 1e-3f * g / (fabsf(g) + 1e-8f);
    Wnb[idx] = f2bf(o);
}

// ---------------- MFMA flash sliding-window attention ----------------
// S^T = K@Q^T (A=K natural, B=Q natural); softmax on C-layout strip; P via wave-private LDS; O=P@V (B=Vt).
__global__ __launch_bounds__(256)
void swa_mfma(const ushort_t* __restrict__ qh, const ushort_t* __restrict__ kh,
              const ushort_t* __restrict__ vhT, float* __restrict__ ao) {
    __shared__ ushort_t Qs[64 * 64];
    __shared__ ushort_t Ks[64 * 64];
    __shared__ ushort_t Vs[64 * 64];      // [dim][key] (transposed), swizzled
    __shared__ ushort_t Pw[4][16 * 72];   // wave-private P strips
    int qt = 32 - (int)blockIdx.x;        // longest first
    int hh = blockIdx.y;
    int b  = blockIdx.z;
    int tid = threadIdx.x;
    int wave = tid >> 6, lane = tid & 63;
    int fr = lane & 15, fq = lane >> 4;
    int tok = tid & 63, cs0 = tid >> 6;

    {   // stage Q tile [query][dim]
        const ushort_t* src = qh + ((size_t)(b * T_ + qt * 64 + tok)) * 512 + hh * 64;
#pragma unroll
        for (int p = 0; p < 2; ++p) {
            int seg = cs0 + p * 4;
            *(int4*)&Qs[tok * 64 + ((seg ^ (tok & 7)) << 3)] = *(const int4*)(src + seg * 8);
        }
    }
    __syncthreads();
    s16x8 qf0 = *(const s16x8*)&Qs[(wave * 16 + fr) * 64 + (((0 + fq) ^ (fr & 7)) << 3)];
    s16x8 qf1 = *(const s16x8*)&Qs[(wave * 16 + fr) * 64 + (((4 + fq) ^ (fr & 7)) << 3)];

    int i_q = qt * 64 + wave * 16 + fr;
    float m_i = -1e30f, l_i = 0.f;
    f32x4 o[4] = {};
    int jstart = qt * 64 - (WIN_ - 1);
    if (jstart < 0) jstart = 0;
    jstart &= ~63;
    for (int jb = jstart; jb <= qt * 64; jb += 64) {
        __syncthreads();
        {
            const ushort_t* ksrc = kh + ((size_t)(b * T_ + jb + tok)) * 512 + hh * 64;
            const ushort_t* vsrc = vhT + ((size_t)(b * 512 + hh * 64 + tok)) * T_ + jb;
#pragma unroll
            for (int p = 0; p < 2; ++p) {
                int seg = cs0 + p * 4;
                *(int4*)&Ks[tok * 64 + ((seg ^ (tok & 7)) << 3)] = *(const int4*)(ksrc + seg * 8);
                *(int4*)&Vs[tok * 64 + ((seg ^ (tok & 7)) << 3)] = *(const int4*)(vsrc + seg * 8);
            }
        }
        __syncthreads();
        // S^T: 64 keys x 16 queries (this wave)
        f32x4 sa[4] = {};
#pragma unroll
        for (int kf = 0; kf < 4; ++kf) {
            int krow = kf * 16 + fr;
            s16x8 a0 = *(const s16x8*)&Ks[krow * 64 + (((0 + fq) ^ (fr & 7)) << 3)];
            s16x8 a1 = *(const s16x8*)&Ks[krow * 64 + (((4 + fq) ^ (fr & 7)) << 3)];
            sa[kf] = __builtin_amdgcn_mfma_f32_16x16x32_bf16(a0, qf0, sa[kf], 0, 0, 0);
            sa[kf] = __builtin_amdgcn_mfma_f32_16x16x32_bf16(a1, qf1, sa[kf], 0, 0, 0);
        }
        // mask + online softmax stats (query = fr, replicated over quads)
        float sv[16];
        float tmax = -1e30f;
#pragma unroll
        for (int kf = 0; kf < 4; ++kf)
#pragma unroll
            for (int r = 0; r < 4; ++r) {
                int j2 = jb + kf * 16 + fq * 4 + r;
                bool valid = (j2 <= i_q) && (i_q - j2 < WIN_);
                float v = valid ? sa[kf][r] * 0.125f : -1e30f;
                sv[kf * 4 + r] = v;
                tmax = fmaxf(tmax, v);
            }
        tmax = fmaxf(tmax, __shfl_xor(tmax, 16));
        tmax = fmaxf(tmax, __shfl_xor(tmax, 32));
        float mn = fmaxf(m_i, tmax);
        float alpha = __expf(m_i - mn);
        m_i = mn;
        float psum = 0.f;
#pragma unroll
        for (int kf = 0; kf < 4; ++kf)
#pragma unroll
            for (int r = 0; r < 4; ++r) {
                float v = sv[kf * 4 + r];
                float p = (v > -1e29f) ? __expf(v - mn) : 0.f;
                ushort_t pb = f2bf(p);
                psum += bf2f(pb);            // match numerator rounding
                Pw[wave][fr * 72 + kf * 16 + fq * 4 + r] = pb;
            }
        psum += __shfl_xor(psum, 16);
        psum += __shfl_xor(psum, 32);
        l_i = l_i * alpha + psum;
        // rescale O (O rows = queries fq*4+r -> fetch alpha from lane fq*4+r)
        float a0s = __shfl(alpha, fq * 4 + 0);
        float a1s = __shfl(alpha, fq * 4 + 1);
        float a2s = __shfl(alpha, fq * 4 + 2);
        float a3s = __shfl(alpha, fq * 4 + 3);
#pragma unroll
        for (int nf = 0; nf < 4; ++nf) {
            o[nf][0] *= a0s; o[nf][1] *= a1s; o[nf][2] *= a2s; o[nf][3] *= a3s;
        }
        // O += P @ V
#pragma unroll
        for (int ks = 0; ks < 2; ++ks) {
            s16x8 pa = *(const s16x8*)&Pw[wave][fr * 72 + ks * 32 + fq * 8];
#pragma unroll
            for (int nf = 0; nf < 4; ++nf) {
                int vrow = nf * 16 + fr;   // dim row in Vt
                s16x8 bv = *(const s16x8*)&Vs[vrow * 64 + (((ks * 4 + fq) ^ (fr & 7)) << 3)];
                o[nf] = __builtin_amdgcn_mfma_f32_16x16x32_bf16(pa, bv, o[nf], 0, 0, 0);
            }
        }
    }
    float linv = 1.0f / l_i;
    float l0 = __shfl(linv, fq * 4 + 0);
    float l1 = __shfl(linv, fq * 4 + 1);
    float l2 = __shfl(linv, fq * 4 + 2);
    float l3 = __shfl(linv, fq * 4 + 3);
#pragma unroll
    for (int nf = 0; nf < 4; ++nf) {
        int col = hh * 64 + nf * 16 + fr;
        int row0 = qt * 64 + wave * 16 + fq * 4;
        ao[((size_t)(b * T_) + row0 + 0) * 512 + col] = o[nf][0] * l0;
        ao[((size_t)(b * T_) + row0 + 1) * 512 + col] = o[nf][1] * l1;
        ao[((size_t)(b * T_) + row0 + 2) * 512 + col] = o[nf][2] * l2;
        ao[((size_t)(b * T_) + row0 + 3) * 512 + col] = o[nf][3] * l3;
    }
}

// ---------------- final fp32 GEMM: out = ao @ wo^T, drop meta rows ----------------
__global__ __launch_bounds__(256)
void gemm_wo(const float* __restrict__ A, const float* __restrict__ Bm, float* __restrict__ C) {
    __shared__ float As[16][68];
    __shared__ float Bs[16][68];
    int tid = threadIdx.x;
    int m0 = blockIdx.x * 64, n0 = blockIdx.y * 64;
    int alm = tid >> 2;
    int alk = (tid & 3) << 2;
    int tm = (tid & 15) << 2;
    int tn = (tid >> 4) << 2;
    float acc[4][4] = {};
    for (int k0 = 0; k0 < 512; k0 += 16) {
        float4 av = *(const float4*)&A[(size_t)(m0 + alm) * 512 + k0 + alk];
        float4 bv = *(const float4*)&Bm[(size_t)(n0 + alm) * 512 + k0 + alk];
        __syncthreads();
        As[alk + 0][alm] = av.x; As[alk + 1][alm] = av.y;
        As[alk + 2][alm] = av.z; As[alk + 3][alm] = av.w;
        Bs[alk + 0][alm] = bv.x; Bs[alk + 1][alm] = bv.y;
        Bs[alk + 2][alm] = bv.z; Bs[alk + 3][alm] = bv.w;
        __syncthreads();
#pragma unroll
        for (int kk = 0; kk < 16; ++kk) {
            float4 a = *(const float4*)&As[kk][tm];
            float4 b = *(const float4*)&Bs[kk][tn];
            acc[0][0] = fmaf(a.x,b.x,acc[0][0]); acc[0][1] = fmaf(a.x,b.y,acc[0][1]);
            acc[0][2] = fmaf(a.x,b.z,acc[0][2]); acc[0][3] = fmaf(a.x,b.w,acc[0][3]);
            acc[1][0] = fmaf(a.y,b.x,acc[1][0]); acc[1][1] = fmaf(a.y,b.y,acc[1][1]);
            acc[1][2] = fmaf(a.y,b.z,acc[1][2]); acc[1][3] = fmaf(a.y,b.w,acc[1][3]);
            acc[2][0] = fmaf(a.z,b.x,acc[2][0]); acc[2][1] = fmaf(a.z,b.y,acc[2][1]);
            acc[2][2] = fmaf(a.z,b.z,acc[2][2]); acc[2][3] = fmaf(a.z,b.w,acc[2][3]);
            acc[3][0] = fmaf(a.w,b.x,acc[3][0]); acc[3][1] = fmaf(a.w,b.y,acc[3][1]);
            acc[3][2] = fmaf(a.w,b.z,acc[3][2]); acc[3][3] = fmaf(a.w,b.w,acc[3][3]);
        }
    }
#pragma unroll
    for (int i = 0; i < 4; ++i) {
        int row = m0 + tm + i;
        int b = row / T_;
        int t = row - b * T_;
        if (t >= M_) {
            float4 o; o.x = acc[i][0]; o.y = acc[i][1]; o.z = acc[i][2]; o.w = acc[i][3];
            *(float4*)&C[((size_t)b * S_ + (t - M_)) * 512 + n0 + tn] = o;
        }
    }
}

extern "C" void kernel_launch(void* const* d_in, const int* in_sizes, int n_in,
                              void* d_out, int out_size, void* d_ws, size_t ws_size,
                              hipStream_t stream) {
    (void)in_sizes; (void)n_in; (void)out_size; (void)ws_size;
    const float* x      = (const float*)d_in[0];
    const float* meta   = (const float*)d_in[1];
    const float* lmm_w  = (const float*)d_in[2];
    const float* w_q    = (const float*)d_in[3];
    const float* w_k    = (const float*)d_in[4];
    const float* w_v    = (const float*)d_in[5];
    const float* w_lr   = (const float*)d_in[6];
    const float* swa_wq = (const float*)d_in[7];
    const float* swa_wk = (const float*)d_in[8];
    const float* swa_wv = (const float*)d_in[9];
    const float* swa_wo = (const float*)d_in[10];
    float* out = (float*)d_out;
    float* ws  = (float*)d_ws;

    const size_t BTD = (size_t)BT_ * D_;       // 2162688
    float* b2 = ws + 0 * BTD;                  // kk f32
    float* b4 = ws + 1 * BTD;                  // z0 -> ao
    float* b5 = ws + 2 * BTD;                  // h1 f32
    float* b6 = ws + 3 * BTD;                  // z1 f32
    float* b7 = ws + 4 * BTD;                  // dp -> dh1
    float* alr = ws + 5 * BTD;                 // BT_
    float* dWp = alr + BT_;                    // [2][6][262144] fp32
    // bf16 region
    ushort_t* xb = (ushort_t*)(dWp + 12 * 262144);
    ushort_t* xm_bf  = xb + 0 * BTD;           // -> r_bf
    ushort_t* qq_bf  = xb + 1 * BTD;           // -> qh_bf
    ushort_t* kk_bf  = xb + 2 * BTD;           // -> h1q_bf
    ushort_t* vv_bf  = xb + 3 * BTD;           // -> dz0_bf
    ushort_t* h1_bf  = xb + 4 * BTD;           // -> vhT
    ushort_t* dz1_bf = xb + 5 * BTD;           // -> kh_bf
    ushort_t* r_bf   = xm_bf;
    ushort_t* h1q_bf = kk_bf;
    ushort_t* qh_bf  = qq_bf;
    ushort_t* kh_bf  = dz1_bf;
    ushort_t* dz0_bf = vv_bf;
    ushort_t* vhT    = h1_bf;
    ushort_t* wbf = xb + 6 * BTD;
    ushort_t* wq_bf  = wbf + 0 * 262144;
    ushort_t* wk_bf  = wbf + 1 * 262144;
    ushort_t* wv_bf  = wbf + 2 * 262144;
    ushort_t* l0_bf  = wbf + 3 * 262144;
    ushort_t* l1_bf  = wbf + 4 * 262144;
    ushort_t* sq_bf  = wbf + 5 * 262144;
    ushort_t* sk_bf  = wbf + 6 * 262144;
    ushort_t* sv_bf  = wbf + 7 * 262144;
    ushort_t* l1t_bf = wbf + 8 * 262144;
    ushort_t* wn_bf  = wbf + 9 * 262144;       // 2 layers

    dim3 blk(256);
    dim3 g8(1056);
    dim3 gg(66, 8);
    dim3 gtn(8, 8, 6);

    W8 wl;
    wl.s[0] = w_q;    wl.d[0] = wq_bf;
    wl.s[1] = w_k;    wl.d[1] = wk_bf;
    wl.s[2] = w_v;    wl.d[2] = wv_bf;
    wl.s[3] = lmm_w;  wl.d[3] = l0_bf;
    wl.s[4] = lmm_w + 262144; wl.d[4] = l1_bf;
    wl.s[5] = swa_wq; wl.d[5] = sq_bf;
    wl.s[6] = swa_wk; wl.d[6] = sk_bf;
    wl.s[7] = swa_wv; wl.d[7] = sv_bf;

    cvt_w_kernel<<<dim3(128, 8), blk, 0, stream>>>(wl);
    cvt_wT_kernel<<<dim3(16, 16), blk, 0, stream>>>(lmm_w + 262144, l1t_bf);
    build_xm_kernel<<<g8, blk, 0, stream>>>(x, meta, xm_bf);
    alr_kernel<<<dim3(1056), blk, 0, stream>>>(xm_bf, w_lr, alr);
    mgemm<0,0,1,0,0><<<gg, blk, 0, stream>>>(xm_bf, wq_bf, nullptr, qq_bf, nullptr, nullptr, nullptr, nullptr);
    mgemm<0,1,1,0,0><<<gg, blk, 0, stream>>>(xm_bf, wk_bf, b2, kk_bf, nullptr, nullptr, nullptr, nullptr);
    mgemm<0,0,1,0,0><<<gg, blk, 0, stream>>>(xm_bf, wv_bf, nullptr, vv_bf, nullptr, nullptr, nullptr, nullptr);
    mgemm<1,1,1,1,0><<<gg, blk, 0, stream>>>(kk_bf, l0_bf, b5, h1_bf, nullptr, b2, nullptr, b4);   // h1, z0
    mgemm<0,1,0,0,0><<<gg, blk, 0, stream>>>(h1_bf, l1_bf, b6, nullptr, nullptr, nullptr, nullptr, nullptr); // z1
    dpdz1_kernel<<<g8, blk, 0, stream>>>(b5, b6, vv_bf, alr, b7, dz1_bf);
    mgemm<3,1,0,0,0><<<gg, blk, 0, stream>>>(dz1_bf, l1t_bf, b7, nullptr, nullptr, b7, nullptr, nullptr);   // dh1
    gemm_tn_bf<<<gtn, blk, 0, stream>>>(dz1_bf, h1_bf, dWp + 6 * 262144);                                   // dW1
    dz0_kernel<<<g8, blk, 0, stream>>>(b7, b4, dz0_bf);
    gemm_tn_bf<<<gtn, blk, 0, stream>>>(dz0_bf, kk_bf, dWp);                                                // dW0
    adam_kernel<<<dim3(2048), blk, 0, stream>>>(lmm_w, dWp, wn_bf);
    mgemm<2,0,1,0,0><<<gg, blk, 0, stream>>>(qq_bf, wn_bf, nullptr, h1q_bf, nullptr, nullptr, qq_bf, nullptr);
    mgemm<2,0,1,0,0><<<gg, blk, 0, stream>>>(h1q_bf, wn_bf + 262144, nullptr, r_bf, nullptr, nullptr, h1q_bf, nullptr);
    mgemm<0,0,1,0,0><<<gg, blk, 0, stream>>>(r_bf, sq_bf, nullptr, qh_bf, nullptr, nullptr, nullptr, nullptr);
    mgemm<0,0,1,0,0><<<gg, blk, 0, stream>>>(r_bf, sk_bf, nullptr, kh_bf, nullptr, nullptr, nullptr, nullptr);
    mgemm<0,0,0,0,1><<<gg, blk, 0, stream>>>(r_bf, sv_bf, nullptr, nullptr, vhT, nullptr, nullptr, nullptr);
    swa_mfma<<<dim3(33, 8, 2), blk, 0, stream>>>(qh_bf, kh_bf, vhT, b4);                                    // ao
    gemm_wo<<<gg, blk, 0, stream>>>(b4, swa_wo, out);
}

// Round 4
// 246.647 us; speedup vs baseline: 3.5244x; 1.2214x over previous
//
#include <hip/hip_runtime.h>
#include <hip/hip_bf16.h>

#define B_   2
#define S_   2048
#define D_   512
#define M_   64
#define T_   2112
#define BT_  4224
#define H_   8
#define WIN_ 512

typedef short s16x8 __attribute__((ext_vector_type(8)));
typedef float f32x4 __attribute__((ext_vector_type(4)));
typedef unsigned short ushort_t;

__device__ __forceinline__ float siluf(float x) {
    float s = 1.0f / (1.0f + expf(-x));
    return x * s;
}
__device__ __forceinline__ float dsiluf(float x) {
    float s = 1.0f / (1.0f + expf(-x));
    return s * (1.0f + x * (1.0f - s));
}
__device__ __forceinline__ float bf2f(ushort_t u) {
    union { float f; unsigned int i; } x; x.i = ((unsigned int)u) << 16; return x.f;
}
__device__ __forceinline__ ushort_t f2bf(float f) {
    union { float f; unsigned int i; } x; x.f = f;
    unsigned int r = x.i + 0x7FFFu + ((x.i >> 16) & 1u);
    return (ushort_t)(r >> 16);
}
__device__ __forceinline__ void pack8(ushort_t* dst, const float* v) {
    ushort_t tmp[8];
#pragma unroll
    for (int i = 0; i < 8; ++i) tmp[i] = f2bf(v[i]);
    *(int4*)dst = *(const int4*)tmp;
}

// ---------------- build xm_bf = concat(meta, x) in bf16 ----------------
__global__ void build_xm_kernel(const float* __restrict__ x, const float* __restrict__ meta,
                                ushort_t* __restrict__ xmb) {
    int idx = blockIdx.x * 256 + threadIdx.x;
    int seg = idx & 63;
    int row = idx >> 6;
    int b   = row / T_;
    int t   = row - b * T_;
    const float* src;
    if (t < M_) src = meta + (size_t)t * 512 + seg * 8;
    else        src = x + ((size_t)b * S_ + (t - M_)) * 512 + seg * 8;
    float v[8];
    *(float4*)&v[0] = *(const float4*)src;
    *(float4*)&v[4] = *(const float4*)(src + 4);
    pack8(xmb + (size_t)row * 512 + seg * 8, v);
}

// ---------------- weight converts ----------------
struct W9 { const float* s[9]; ushort_t* d[9]; };
__global__ void cvt_w_kernel(W9 p) {
    int w = blockIdx.y;
    int idx = blockIdx.x * 256 + threadIdx.x;
    const float* src = p.s[w] + (size_t)idx * 8;
    float v[8];
    *(float4*)&v[0] = *(const float4*)src;
    *(float4*)&v[4] = *(const float4*)(src + 4);
    pack8(p.d[w] + (size_t)idx * 8, v);
}
// transposed bf16 copy: dst[m][n] = src[n][m]  (512x512)
__global__ void cvt_wT_kernel(const float* __restrict__ src, ushort_t* __restrict__ dst) {
    __shared__ float t[32][33];
    int tid = threadIdx.x;
    int tr = tid >> 3, tc = (tid & 7) * 4;
    int r0 = blockIdx.y * 32, c0 = blockIdx.x * 32;
    *(float4*)&t[tr][tc] = *(const float4*)&src[(size_t)(r0 + tr) * 512 + c0 + tc];
    __syncthreads();
    ushort_t o[4];
#pragma unroll
    for (int i = 0; i < 4; ++i) o[i] = f2bf(t[tc + i][tr]);
    *(ushort2*)&dst[(size_t)(c0 + tr) * 512 + r0 + tc] = *(ushort2*)&o[0];
    *(ushort2*)&dst[(size_t)(c0 + tr) * 512 + r0 + tc + 2] = *(ushort2*)&o[2];
}

// ---------------- alr = sigmoid(xm @ w_lr^T) * 0.01 ----------------
__global__ void alr_kernel(const ushort_t* __restrict__ xmb, const float* __restrict__ wlr,
                           float* __restrict__ alr) {
    int r = blockIdx.x * 4 + (threadIdx.x >> 6);
    int lane = threadIdx.x & 63;
    const ushort_t* row = xmb + (size_t)r * D_;
    float s = 0.f;
#pragma unroll
    for (int k = 0; k < 8; ++k) s = fmaf(bf2f(row[lane + k * 64]), wlr[lane + k * 64], s);
#pragma unroll
    for (int off = 32; off >= 1; off >>= 1) s += __shfl_xor(s, off, 64);
    if (lane == 0) alr[r] = 0.01f / (1.0f + expf(-s));
}

// ---------------- bf16 MFMA GEMM with fused epilogues ----------------
// MODE 0 QKV (N=1536, 3 bf16 outs); 1 H1 (z0->F1, h1->F0+U0, res=bf U1);
// 2 Z1DP (dp->F1, dz1->U0; reads h1=F0, v=U1, alr); 3 DH1DZ0 (dz0->U0; reads dp=F0, z0=F1);
// 4 RES2 (U0 = bf(U1)+silu(acc)); 5 SWAQKV (N=1536: qh->U0, kh->U1, vhT->U2);
// 6 WO (row-filtered fp32 out->F0)
template<int MODE>
__global__ __launch_bounds__(256)
void mgemm(const ushort_t* __restrict__ A, const ushort_t* __restrict__ Bt,
           float* __restrict__ F0, float* __restrict__ F1,
           ushort_t* __restrict__ U0, ushort_t* __restrict__ U1, ushort_t* __restrict__ U2,
           const float* __restrict__ alrp) {
    __shared__ ushort_t As[64 * 64];
    __shared__ ushort_t Bs[64 * 64];
    int tid = threadIdx.x;
    int m0 = blockIdx.x * 64, n0 = blockIdx.y * 64;
    int srow = tid >> 2;
    int sseg = (tid & 3) << 1;
    int wid = tid >> 6;
    int lane = tid & 63;
    int wm = (wid & 1) << 5;
    int wn = (wid >> 1) << 5;
    int fr = lane & 15;
    int fq = lane >> 4;
    f32x4 acc[2][2] = {};
    for (int k0 = 0; k0 < 512; k0 += 64) {
        const ushort_t* ga = A  + (size_t)(m0 + srow) * 512 + k0 + sseg * 8;
        const ushort_t* gb = Bt + (size_t)(n0 + srow) * 512 + k0 + sseg * 8;
        int4 av0 = *(const int4*)ga;
        int4 av1 = *(const int4*)(ga + 8);
        int4 bv0 = *(const int4*)gb;
        int4 bv1 = *(const int4*)(gb + 8);
        __syncthreads();
        int sw = srow & 7;
        *(int4*)&As[srow * 64 + ((sseg    ) ^ sw) * 8] = av0;
        *(int4*)&As[srow * 64 + ((sseg + 1) ^ sw) * 8] = av1;
        *(int4*)&Bs[srow * 64 + ((sseg    ) ^ sw) * 8] = bv0;
        *(int4*)&Bs[srow * 64 + ((sseg + 1) ^ sw) * 8] = bv1;
        __syncthreads();
#pragma unroll
        for (int ks = 0; ks < 2; ++ks) {
            int seg = fq + ks * 4;
            int rA0 = wm + fr,      rA1 = wm + 16 + fr;
            int rB0 = wn + fr,      rB1 = wn + 16 + fr;
            s16x8 a0 = *(const s16x8*)&As[rA0 * 64 + (seg ^ (rA0 & 7)) * 8];
            s16x8 a1 = *(const s16x8*)&As[rA1 * 64 + (seg ^ (rA1 & 7)) * 8];
            s16x8 b0 = *(const s16x8*)&Bs[rB0 * 64 + (seg ^ (rB0 & 7)) * 8];
            s16x8 b1 = *(const s16x8*)&Bs[rB1 * 64 + (seg ^ (rB1 & 7)) * 8];
            acc[0][0] = __builtin_amdgcn_mfma_f32_16x16x32_bf16(a0, b0, acc[0][0], 0, 0, 0);
            acc[0][1] = __builtin_amdgcn_mfma_f32_16x16x32_bf16(a0, b1, acc[0][1], 0, 0, 0);
            acc[1][0] = __builtin_amdgcn_mfma_f32_16x16x32_bf16(a1, b0, acc[1][0], 0, 0, 0);
            acc[1][1] = __builtin_amdgcn_mfma_f32_16x16x32_bf16(a1, b1, acc[1][1], 0, 0, 0);
        }
    }
#pragma unroll
    for (int i = 0; i < 2; ++i) {
        int row0 = m0 + wm + i * 16 + fq * 4;
        float c4[4];
        if (MODE == 2) {
#pragma unroll
            for (int r = 0; r < 4; ++r) c4[r] = (2.0f / 512.0f) * alrp[row0 + r];
        }
#pragma unroll
        for (int j = 0; j < 2; ++j) {
            int col = n0 + wn + j * 16 + fr;
            if (MODE == 0 || MODE == 5) {
                int sg = col >> 9;
                int cl = col & 511;
                if (MODE == 0) {
                    ushort_t* dst = (sg == 0) ? U0 : ((sg == 1) ? U1 : U2);
#pragma unroll
                    for (int r = 0; r < 4; ++r)
                        dst[(size_t)(row0 + r) * 512 + cl] = f2bf(acc[i][j][r]);
                } else {
                    if (sg == 0) {
#pragma unroll
                        for (int r = 0; r < 4; ++r)
                            U0[(size_t)(row0 + r) * 512 + cl] = f2bf(acc[i][j][r]);
                    } else if (sg == 1) {
#pragma unroll
                        for (int r = 0; r < 4; ++r)
                            U1[(size_t)(row0 + r) * 512 + cl] = f2bf(acc[i][j][r]);
                    } else {
                        int bb = row0 / T_;
                        int t0 = row0 - bb * T_;
                        ushort_t t4[4];
#pragma unroll
                        for (int r = 0; r < 4; ++r) t4[r] = f2bf(acc[i][j][r]);
                        *(uint2*)&U2[((size_t)(bb * 512) + cl) * T_ + t0] = *(uint2*)t4;
                    }
                }
            } else {
#pragma unroll
                for (int r = 0; r < 4; ++r) {
                    size_t off = (size_t)(row0 + r) * 512 + col;
                    float v = acc[i][j][r];
                    if (MODE == 1) {
                        F1[off] = v;
                        float h = bf2f(U1[off]) + siluf(v);
                        F0[off] = h;
                        U0[off] = f2bf(h);
                    } else if (MODE == 2) {
                        float z = v;
                        float s = 1.f / (1.f + expf(-z));
                        float d = c4[r] * (F0[off] + z * s - bf2f(U1[off]));
                        F1[off] = d;
                        U0[off] = f2bf(d * (s * (1.f + z * (1.f - s))));
                    } else if (MODE == 3) {
                        float g = F0[off] + v;
                        U0[off] = f2bf(g * dsiluf(F1[off]));
                    } else if (MODE == 4) {
                        U0[off] = f2bf(bf2f(U1[off]) + siluf(v));
                    } else if (MODE == 6) {
                        int row = row0 + r;
                        int bb = row / T_;
                        int t = row - bb * T_;
                        if (t >= M_) F0[((size_t)bb * S_ + (t - M_)) * 512 + col] = v;
                    }
                }
            }
        }
    }
}

// ---------------- bf16 MFMA TN GEMM for dW: C[m][n] = sum_t A[t][m] B[t][n], split-K x6 ----------------
__global__ __launch_bounds__(256)
void gemm_tn_bf(const ushort_t* __restrict__ A, const ushort_t* __restrict__ Bm,
                float* __restrict__ Cpart) {
    __shared__ ushort_t At[64 * 64];
    __shared__ ushort_t Bt[64 * 64];
    int tid = threadIdx.x;
    int m0 = blockIdx.x * 64, n0 = blockIdx.y * 64;
    int kbase = blockIdx.z * 704;
    int wave = tid >> 6, lane = tid & 63;
    int fr = lane & 15, fq = lane >> 4;
    int wm = (wave & 1) << 5, wn = (wave >> 1) << 5;
    int tok = tid & 63, cs0 = tid >> 6;
    f32x4 acc[2][2] = {};
    for (int kt = 0; kt < 11; ++kt) {
        int t0 = kbase + kt * 64;
        int4 av[2], bv[2];
#pragma unroll
        for (int p = 0; p < 2; ++p) {
            int cs = cs0 + p * 4;
            av[p] = *(const int4*)&A[(size_t)(t0 + tok) * 512 + m0 + cs * 8];
            bv[p] = *(const int4*)&Bm[(size_t)(t0 + tok) * 512 + n0 + cs * 8];
        }
        __syncthreads();
#pragma unroll
        for (int p = 0; p < 2; ++p) {
            int cs = cs0 + p * 4;
            const ushort_t* au = (const ushort_t*)&av[p];
            const ushort_t* bu = (const ushort_t*)&bv[p];
#pragma unroll
            for (int j = 0; j < 8; ++j) {
                int row = cs * 8 + j;
                At[row * 64 + (((tok >> 3) ^ j) << 3) + (tok & 7)] = au[j];
                Bt[row * 64 + (((tok >> 3) ^ j) << 3) + (tok & 7)] = bu[j];
            }
        }
        __syncthreads();
#pragma unroll
        for (int ks = 0; ks < 2; ++ks) {
            int seg = ks * 4 + fq;
            s16x8 a0 = *(const s16x8*)&At[(wm + fr) * 64      + ((seg ^ (fr & 7)) << 3)];
            s16x8 a1 = *(const s16x8*)&At[(wm + 16 + fr) * 64 + ((seg ^ (fr & 7)) << 3)];
            s16x8 b0 = *(const s16x8*)&Bt[(wn + fr) * 64      + ((seg ^ (fr & 7)) << 3)];
            s16x8 b1 = *(const s16x8*)&Bt[(wn + 16 + fr) * 64 + ((seg ^ (fr & 7)) << 3)];
            acc[0][0] = __builtin_amdgcn_mfma_f32_16x16x32_bf16(a0, b0, acc[0][0], 0, 0, 0);
            acc[0][1] = __builtin_amdgcn_mfma_f32_16x16x32_bf16(a0, b1, acc[0][1], 0, 0, 0);
            acc[1][0] = __builtin_amdgcn_mfma_f32_16x16x32_bf16(a1, b0, acc[1][0], 0, 0, 0);
            acc[1][1] = __builtin_amdgcn_mfma_f32_16x16x32_bf16(a1, b1, acc[1][1], 0, 0, 0);
        }
    }
    float* C = Cpart + (size_t)blockIdx.z * 262144;
#pragma unroll
    for (int i = 0; i < 2; ++i)
#pragma unroll
        for (int j = 0; j < 2; ++j)
#pragma unroll
            for (int r = 0; r < 4; ++r)
                C[(size_t)(m0 + wm + i * 16 + fq * 4 + r) * 512 + n0 + wn + j * 16 + fr] =
                    acc[i][j][r];
}

// ---------------- AdamW first step (6 partial slices) -> bf16 weights ----------------
__global__ void adam_kernel(const float* __restrict__ W, const float* __restrict__ dWp,
                            ushort_t* __restrict__ Wnb) {
    int idx = blockIdx.x * 256 + threadIdx.x;
    int layer = idx >> 18;
    int i = idx & 262143;
    const float* base = dWp + (size_t)layer * 6 * 262144 + i;
    float g = 0.f;
#pragma unroll
    for (int z = 0; z < 6; ++z) g += base[(size_t)z * 262144];
    g *= (1.0f / 16.0f);
    float w = W[idx];
    float o = w * (1.0f - 1e-5f) - 1e-3f * g / (fabsf(g) + 1e-8f);
    Wnb[idx] = f2bf(o);
}

// ---------------- MFMA flash sliding-window attention (bf16 out) ----------------
__global__ __launch_bounds__(256)
void swa_mfma(const ushort_t* __restrict__ qh, const ushort_t* __restrict__ kh,
              const ushort_t* __restrict__ vhT, ushort_t* __restrict__ ao) {
    __shared__ ushort_t Qs[64 * 64];
    __shared__ ushort_t Ks[64 * 64];
    __shared__ ushort_t Vs[64 * 64];
    __shared__ ushort_t Pw[4][16 * 72];
    int qt = 32 - (int)blockIdx.x;
    int hh = blockIdx.y;
    int b  = blockIdx.z;
    int tid = threadIdx.x;
    int wave = tid >> 6, lane = tid & 63;
    int fr = lane & 15, fq = lane >> 4;
    int tok = tid & 63, cs0 = tid >> 6;

    {
        const ushort_t* src = qh + ((size_t)(b * T_ + qt * 64 + tok)) * 512 + hh * 64;
#pragma unroll
        for (int p = 0; p < 2; ++p) {
            int seg = cs0 + p * 4;
            *(int4*)&Qs[tok * 64 + ((seg ^ (tok & 7)) << 3)] = *(const int4*)(src + seg * 8);
        }
    }
    __syncthreads();
    s16x8 qf0 = *(const s16x8*)&Qs[(wave * 16 + fr) * 64 + (((0 + fq) ^ (fr & 7)) << 3)];
    s16x8 qf1 = *(const s16x8*)&Qs[(wave * 16 + fr) * 64 + (((4 + fq) ^ (fr & 7)) << 3)];

    int i_q = qt * 64 + wave * 16 + fr;
    float m_i = -1e30f, l_i = 0.f;
    f32x4 o[4] = {};
    int jstart = qt * 64 - (WIN_ - 1);
    if (jstart < 0) jstart = 0;
    jstart &= ~63;
    for (int jb = jstart; jb <= qt * 64; jb += 64) {
        __syncthreads();
        {
            const ushort_t* ksrc = kh + ((size_t)(b * T_ + jb + tok)) * 512 + hh * 64;
            const ushort_t* vsrc = vhT + ((size_t)(b * 512 + hh * 64 + tok)) * T_ + jb;
#pragma unroll
            for (int p = 0; p < 2; ++p) {
                int seg = cs0 + p * 4;
                *(int4*)&Ks[tok * 64 + ((seg ^ (tok & 7)) << 3)] = *(const int4*)(ksrc + seg * 8);
                *(int4*)&Vs[tok * 64 + ((seg ^ (tok & 7)) << 3)] = *(const int4*)(vsrc + seg * 8);
            }
        }
        __syncthreads();
        f32x4 sa[4] = {};
#pragma unroll
        for (int kf = 0; kf < 4; ++kf) {
            int krow = kf * 16 + fr;
            s16x8 a0 = *(const s16x8*)&Ks[krow * 64 + (((0 + fq) ^ (fr & 7)) << 3)];
            s16x8 a1 = *(const s16x8*)&Ks[krow * 64 + (((4 + fq) ^ (fr & 7)) << 3)];
            sa[kf] = __builtin_amdgcn_mfma_f32_16x16x32_bf16(a0, qf0, sa[kf], 0, 0, 0);
            sa[kf] = __builtin_amdgcn_mfma_f32_16x16x32_bf16(a1, qf1, sa[kf], 0, 0, 0);
        }
        float sv[16];
        float tmax = -1e30f;
#pragma unroll
        for (int kf = 0; kf < 4; ++kf)
#pragma unroll
            for (int r = 0; r < 4; ++r) {
                int j2 = jb + kf * 16 + fq * 4 + r;
                bool valid = (j2 <= i_q) && (i_q - j2 < WIN_);
                float v = valid ? sa[kf][r] * 0.125f : -1e30f;
                sv[kf * 4 + r] = v;
                tmax = fmaxf(tmax, v);
            }
        tmax = fmaxf(tmax, __shfl_xor(tmax, 16));
        tmax = fmaxf(tmax, __shfl_xor(tmax, 32));
        float mn = fmaxf(m_i, tmax);
        float alpha = __expf(m_i - mn);
        m_i = mn;
        float psum = 0.f;
#pragma unroll
        for (int kf = 0; kf < 4; ++kf)
#pragma unroll
            for (int r = 0; r < 4; ++r) {
                float v = sv[kf * 4 + r];
                float p = (v > -1e29f) ? __expf(v - mn) : 0.f;
                ushort_t pb = f2bf(p);
                psum += bf2f(pb);
                Pw[wave][fr * 72 + kf * 16 + fq * 4 + r] = pb;
            }
        psum += __shfl_xor(psum, 16);
        psum += __shfl_xor(psum, 32);
        l_i = l_i * alpha + psum;
        float a0s = __shfl(alpha, fq * 4 + 0);
        float a1s = __shfl(alpha, fq * 4 + 1);
        float a2s = __shfl(alpha, fq * 4 + 2);
        float a3s = __shfl(alpha, fq * 4 + 3);
#pragma unroll
        for (int nf = 0; nf < 4; ++nf) {
            o[nf][0] *= a0s; o[nf][1] *= a1s; o[nf][2] *= a2s; o[nf][3] *= a3s;
        }
#pragma unroll
        for (int ks = 0; ks < 2; ++ks) {
            s16x8 pa = *(const s16x8*)&Pw[wave][fr * 72 + ks * 32 + fq * 8];
#pragma unroll
            for (int nf = 0; nf < 4; ++nf) {
                int vrow = nf * 16 + fr;
                s16x8 bv = *(const s16x8*)&Vs[vrow * 64 + (((ks * 4 + fq) ^ (fr & 7)) << 3)];
                o[nf] = __builtin_amdgcn_mfma_f32_16x16x32_bf16(pa, bv, o[nf], 0, 0, 0);
            }
        }
    }
    float linv = 1.0f / l_i;
    float l0 = __shfl(linv, fq * 4 + 0);
    float l1 = __shfl(linv, fq * 4 + 1);
    float l2 = __shfl(linv, fq * 4 + 2);
    float l3 = __shfl(linv, fq * 4 + 3);
#pragma unroll
    for (int nf = 0; nf < 4; ++nf) {
        int col = hh * 64 + nf * 16 + fr;
        size_t row0 = (size_t)(b * T_) + qt * 64 + wave * 16 + fq * 4;
        ao[(row0 + 0) * 512 + col] = f2bf(o[nf][0] * l0);
        ao[(row0 + 1) * 512 + col] = f2bf(o[nf][1] * l1);
        ao[(row0 + 2) * 512 + col] = f2bf(o[nf][2] * l2);
        ao[(row0 + 3) * 512 + col] = f2bf(o[nf][3] * l3);
    }
}

extern "C" void kernel_launch(void* const* d_in, const int* in_sizes, int n_in,
                              void* d_out, int out_size, void* d_ws, size_t ws_size,
                              hipStream_t stream) {
    (void)in_sizes; (void)n_in; (void)out_size; (void)ws_size;
    const float* x      = (const float*)d_in[0];
    const float* meta   = (const float*)d_in[1];
    const float* lmm_w  = (const float*)d_in[2];
    const float* w_q    = (const float*)d_in[3];
    const float* w_k    = (const float*)d_in[4];
    const float* w_v    = (const float*)d_in[5];
    const float* w_lr   = (const float*)d_in[6];
    const float* swa_wq = (const float*)d_in[7];
    const float* swa_wk = (const float*)d_in[8];
    const float* swa_wv = (const float*)d_in[9];
    const float* swa_wo = (const float*)d_in[10];
    float* out = (float*)d_out;
    float* ws  = (float*)d_ws;

    const size_t BTD = (size_t)BT_ * D_;       // 2162688
    float* b4 = ws + 0 * BTD;                  // z0 f32
    float* b5 = ws + 1 * BTD;                  // h1 f32
    float* b7 = ws + 2 * BTD;                  // dp f32
    float* alr = ws + 3 * BTD;                 // BT_
    float* dWp = alr + BT_;                    // [2][6][262144] fp32
    ushort_t* xb = (ushort_t*)(dWp + 12 * 262144);
    ushort_t* xm_bf  = xb + 0 * BTD;           // -> r_bf
    ushort_t* qq_bf  = xb + 1 * BTD;           // -> qh_bf
    ushort_t* kk_bf  = xb + 2 * BTD;           // -> h1q_bf
    ushort_t* vv_bf  = xb + 3 * BTD;           // -> dz0_bf -> ao_bf
    ushort_t* h1_bf  = xb + 4 * BTD;           // -> vhT
    ushort_t* dz1_bf = xb + 5 * BTD;           // -> kh_bf
    ushort_t* r_bf   = xm_bf;
    ushort_t* h1q_bf = kk_bf;
    ushort_t* qh_bf  = qq_bf;
    ushort_t* kh_bf  = dz1_bf;
    ushort_t* dz0_bf = vv_bf;
    ushort_t* ao_bf  = vv_bf;
    ushort_t* vhT    = h1_bf;
    ushort_t* wbf = xb + 6 * BTD;
    ushort_t* wq_bf  = wbf + 0 * 262144;       // wq,wk,wv contiguous (QKV fused B)
    ushort_t* l0_bf  = wbf + 3 * 262144;
    ushort_t* l1_bf  = wbf + 4 * 262144;
    ushort_t* sq_bf  = wbf + 5 * 262144;       // sq,sk,sv contiguous (SWAQKV fused B)
    ushort_t* wo_bf  = wbf + 8 * 262144;
    ushort_t* l1t_bf = wbf + 9 * 262144;
    ushort_t* wn_bf  = wbf + 10 * 262144;      // 2 layers

    dim3 blk(256);
    dim3 g8(1056);
    dim3 gg(66, 8);
    dim3 gq(66, 24);
    dim3 gtn(8, 8, 6);

    W9 wl;
    wl.s[0] = w_q;    wl.d[0] = wq_bf;
    wl.s[1] = w_k;    wl.d[1] = wbf + 1 * 262144;
    wl.s[2] = w_v;    wl.d[2] = wbf + 2 * 262144;
    wl.s[3] = lmm_w;  wl.d[3] = l0_bf;
    wl.s[4] = lmm_w + 262144; wl.d[4] = l1_bf;
    wl.s[5] = swa_wq; wl.d[5] = sq_bf;
    wl.s[6] = swa_wk; wl.d[6] = wbf + 6 * 262144;
    wl.s[7] = swa_wv; wl.d[7] = wbf + 7 * 262144;
    wl.s[8] = swa_wo; wl.d[8] = wo_bf;

    cvt_w_kernel<<<dim3(128, 9), blk, 0, stream>>>(wl);
    cvt_wT_kernel<<<dim3(16, 16), blk, 0, stream>>>(lmm_w + 262144, l1t_bf);
    build_xm_kernel<<<g8, blk, 0, stream>>>(x, meta, xm_bf);
    alr_kernel<<<dim3(1056), blk, 0, stream>>>(xm_bf, w_lr, alr);
    // qq/kk/vv = xm @ {wq,wk,wv}^T   (fused, N=1536)
    mgemm<0><<<gq, blk, 0, stream>>>(xm_bf, wq_bf, nullptr, nullptr, qq_bf, kk_bf, vv_bf, nullptr);
    // z0=b4, h1=b5+h1_bf (residual kk_bf)
    mgemm<1><<<gg, blk, 0, stream>>>(kk_bf, l0_bf, b5, b4, h1_bf, kk_bf, nullptr, nullptr);
    // z1 -> fused dp=b7, dz1_bf   (reads h1=b5, v=vv_bf, alr)
    mgemm<2><<<gg, blk, 0, stream>>>(h1_bf, l1_bf, b5, b7, dz1_bf, vv_bf, nullptr, alr);
    // dh1 = dp + dz1@l1 -> fused dz0_bf  (reads dp=b7, z0=b4)
    mgemm<3><<<gg, blk, 0, stream>>>(dz1_bf, l1t_bf, b7, b4, dz0_bf, nullptr, nullptr, nullptr);
    gemm_tn_bf<<<gtn, blk, 0, stream>>>(dz1_bf, h1_bf, dWp + 6 * 262144);   // dW1
    gemm_tn_bf<<<gtn, blk, 0, stream>>>(dz0_bf, kk_bf, dWp);                // dW0
    adam_kernel<<<dim3(2048), blk, 0, stream>>>(lmm_w, dWp, wn_bf);
    // h1q = qq + silu(qq@Wn0^T)
    mgemm<4><<<gg, blk, 0, stream>>>(qq_bf, wn_bf, nullptr, nullptr, h1q_bf, qq_bf, nullptr, nullptr);
    // r = h1q + silu(h1q@Wn1^T)
    mgemm<4><<<gg, blk, 0, stream>>>(h1q_bf, wn_bf + 262144, nullptr, nullptr, r_bf, h1q_bf, nullptr, nullptr);
    // qh/kh/vhT = r @ {sq,sk,sv}^T  (fused, N=1536; vh stored transposed)
    mgemm<5><<<gq, blk, 0, stream>>>(r_bf, sq_bf, nullptr, nullptr, qh_bf, kh_bf, vhT, nullptr);
    swa_mfma<<<dim3(33, 8, 2), blk, 0, stream>>>(qh_bf, kh_bf, vhT, ao_bf);
    // out = ao @ wo^T (row-filtered fp32)
    mgemm<6><<<gg, blk, 0, stream>>>(ao_bf, wo_bf, out, nullptr, nullptr, nullptr, nullptr, nullptr);
}

// Round 5
// 217.569 us; speedup vs baseline: 3.9955x; 1.1336x over previous
//
#include <hip/hip_runtime.h>
#include <hip/hip_bf16.h>

#define B_   2
#define S_   2048
#define D_   512
#define M_   64
#define T_   2112
#define BT_  4224
#define H_   8
#define WIN_ 512

typedef short s16x8 __attribute__((ext_vector_type(8)));
typedef float f32x4 __attribute__((ext_vector_type(4)));
typedef unsigned short ushort_t;

__device__ __forceinline__ float siluf(float x) {
    float s = 1.0f / (1.0f + expf(-x));
    return x * s;
}
__device__ __forceinline__ float dsiluf(float x) {
    float s = 1.0f / (1.0f + expf(-x));
    return s * (1.0f + x * (1.0f - s));
}
__device__ __forceinline__ float bf2f(ushort_t u) {
    union { float f; unsigned int i; } x; x.i = ((unsigned int)u) << 16; return x.f;
}
__device__ __forceinline__ ushort_t f2bf(float f) {
    union { float f; unsigned int i; } x; x.f = f;
    unsigned int r = x.i + 0x7FFFu + ((x.i >> 16) & 1u);
    return (ushort_t)(r >> 16);
}
__device__ __forceinline__ void pack8(ushort_t* dst, const float* v) {
    ushort_t tmp[8];
#pragma unroll
    for (int i = 0; i < 8; ++i) tmp[i] = f2bf(v[i]);
    *(int4*)dst = *(const int4*)tmp;
}

// ---------------- fused prep: weight cvt (9), l1 transpose, xm build, alr ----------------
struct PrepArgs {
    const float* wsrc[9]; ushort_t* wdst[9];
    const float* l1src;   ushort_t* l1t;
    const float* x; const float* meta; ushort_t* xm;
    const float* wlr; float* alr;
};
__global__ __launch_bounds__(256)
void prep_kernel(PrepArgs p) {
    __shared__ float tbuf[32][33];
    int bid = blockIdx.x;
    int tid = threadIdx.x;
    if (bid < 1152) {                       // weight cvt: 9 x 128 blocks
        int w = bid >> 7;
        int idx = ((bid & 127) << 8) + tid;
        const float* src = p.wsrc[w] + (size_t)idx * 8;
        float v[8];
        *(float4*)&v[0] = *(const float4*)src;
        *(float4*)&v[4] = *(const float4*)(src + 4);
        pack8(p.wdst[w] + (size_t)idx * 8, v);
    } else if (bid < 1408) {                // l1 transpose: 256 blocks
        int wz = bid - 1152;
        int bx = wz & 15, by = wz >> 4;
        int tr = tid >> 3, tc = (tid & 7) * 4;
        int r0 = by * 32, c0 = bx * 32;
        *(float4*)&tbuf[tr][tc] = *(const float4*)&p.l1src[(size_t)(r0 + tr) * 512 + c0 + tc];
        __syncthreads();
        ushort_t o[4];
#pragma unroll
        for (int i = 0; i < 4; ++i) o[i] = f2bf(tbuf[tc + i][tr]);
        *(ushort2*)&p.l1t[(size_t)(c0 + tr) * 512 + r0 + tc] = *(ushort2*)&o[0];
        *(ushort2*)&p.l1t[(size_t)(c0 + tr) * 512 + r0 + tc + 2] = *(ushort2*)&o[2];
    } else if (bid < 2464) {                // xm build: 1056 blocks, 8-elem groups
        int idx = (bid - 1408) * 256 + tid;
        int seg = idx & 63;
        int row = idx >> 6;
        int b = row / T_;
        int t = row - b * T_;
        const float* src;
        if (t < M_) src = p.meta + (size_t)t * 512 + seg * 8;
        else        src = p.x + ((size_t)b * S_ + (t - M_)) * 512 + seg * 8;
        float v[8];
        *(float4*)&v[0] = *(const float4*)src;
        *(float4*)&v[4] = *(const float4*)(src + 4);
        pack8(p.xm + (size_t)row * 512 + seg * 8, v);
    } else {                                // alr: 1056 blocks x 4 rows (f32 sources)
        int r = (bid - 2464) * 4 + (tid >> 6);
        int lane = tid & 63;
        int b = r / T_;
        int t = r - b * T_;
        const float* row = (t < M_) ? (p.meta + (size_t)t * 512)
                                    : (p.x + ((size_t)b * S_ + (t - M_)) * 512);
        float s = 0.f;
#pragma unroll
        for (int k = 0; k < 8; ++k) s = fmaf(row[lane + k * 64], p.wlr[lane + k * 64], s);
#pragma unroll
        for (int off = 32; off >= 1; off >>= 1) s += __shfl_xor(s, off, 64);
        if (lane == 0) p.alr[r] = 0.01f / (1.0f + expf(-s));
    }
}

// ---------------- bf16 MFMA GEMM (K=512) with fused epilogues, reg-prefetch pipeline ----------------
// MODE 0 QKV (N=1536: qq->U0, kk->U1+T-major U2, vv->U3)
// MODE 1 H1  (z0->F1, h1->F0 + bf U0 + T-major U2; residual=bf U1)
// MODE 2 Z1DP(dp->F1, dz1->U0 + T-major U2; reads h1=F0, v=U1, alr)
// MODE 3 DH1DZ0 (dz0 T-major->U0; reads dp=F0, z0=F1)
// MODE 4 RES2 (U0 = bf(U1)+silu(acc))
// MODE 5 SWAQKV (N=1536: qh->U0, kh->U1, vhT per-batch transposed->U2)
// MODE 6 WO (row-filtered fp32 out->F0)
template<int MODE>
__global__ __launch_bounds__(256)
void mgemm(const ushort_t* __restrict__ A, const ushort_t* __restrict__ Bt,
           float* __restrict__ F0, float* __restrict__ F1,
           ushort_t* __restrict__ U0, ushort_t* __restrict__ U1,
           ushort_t* __restrict__ U2, ushort_t* __restrict__ U3,
           const float* __restrict__ alrp) {
    __shared__ ushort_t As[64 * 64];
    __shared__ ushort_t Bs[64 * 64];
    int tid = threadIdx.x;
    int m0 = blockIdx.x * 64, n0 = blockIdx.y * 64;
    int srow = tid >> 2;
    int sseg = (tid & 3) << 1;
    int wid = tid >> 6;
    int lane = tid & 63;
    int wm = (wid & 1) << 5;
    int wn = (wid >> 1) << 5;
    int fr = lane & 15;
    int fq = lane >> 4;
    int sw = srow & 7;
    const ushort_t* ga = A  + (size_t)(m0 + srow) * 512 + sseg * 8;
    const ushort_t* gb = Bt + (size_t)(n0 + srow) * 512 + sseg * 8;
    int4 av0 = *(const int4*)ga;
    int4 av1 = *(const int4*)(ga + 8);
    int4 bv0 = *(const int4*)gb;
    int4 bv1 = *(const int4*)(gb + 8);
    f32x4 acc[2][2] = {};
    for (int k0 = 0; k0 < 512; k0 += 64) {
        __syncthreads();
        *(int4*)&As[srow * 64 + ((sseg    ) ^ sw) * 8] = av0;
        *(int4*)&As[srow * 64 + ((sseg + 1) ^ sw) * 8] = av1;
        *(int4*)&Bs[srow * 64 + ((sseg    ) ^ sw) * 8] = bv0;
        *(int4*)&Bs[srow * 64 + ((sseg + 1) ^ sw) * 8] = bv1;
        __syncthreads();
        if (k0 + 64 < 512) {                 // prefetch overlaps MFMA phase
            av0 = *(const int4*)(ga + k0 + 64);
            av1 = *(const int4*)(ga + k0 + 72);
            bv0 = *(const int4*)(gb + k0 + 64);
            bv1 = *(const int4*)(gb + k0 + 72);
        }
#pragma unroll
        for (int ks = 0; ks < 2; ++ks) {
            int seg = fq + ks * 4;
            int rA0 = wm + fr,      rA1 = wm + 16 + fr;
            int rB0 = wn + fr,      rB1 = wn + 16 + fr;
            s16x8 a0 = *(const s16x8*)&As[rA0 * 64 + (seg ^ (rA0 & 7)) * 8];
            s16x8 a1 = *(const s16x8*)&As[rA1 * 64 + (seg ^ (rA1 & 7)) * 8];
            s16x8 b0 = *(const s16x8*)&Bs[rB0 * 64 + (seg ^ (rB0 & 7)) * 8];
            s16x8 b1 = *(const s16x8*)&Bs[rB1 * 64 + (seg ^ (rB1 & 7)) * 8];
            acc[0][0] = __builtin_amdgcn_mfma_f32_16x16x32_bf16(a0, b0, acc[0][0], 0, 0, 0);
            acc[0][1] = __builtin_amdgcn_mfma_f32_16x16x32_bf16(a0, b1, acc[0][1], 0, 0, 0);
            acc[1][0] = __builtin_amdgcn_mfma_f32_16x16x32_bf16(a1, b0, acc[1][0], 0, 0, 0);
            acc[1][1] = __builtin_amdgcn_mfma_f32_16x16x32_bf16(a1, b1, acc[1][1], 0, 0, 0);
        }
    }
#pragma unroll
    for (int i = 0; i < 2; ++i) {
        int row0 = m0 + wm + i * 16 + fq * 4;
        float c4[4];
        if (MODE == 2) {
#pragma unroll
            for (int r = 0; r < 4; ++r) c4[r] = (2.0f / 512.0f) * alrp[row0 + r];
        }
#pragma unroll
        for (int j = 0; j < 2; ++j) {
            int col = n0 + wn + j * 16 + fr;
            if (MODE == 0) {
                int sg = col >> 9, cl = col & 511;
                ushort_t t4[4];
#pragma unroll
                for (int r = 0; r < 4; ++r) t4[r] = f2bf(acc[i][j][r]);
                if (sg == 0) {
#pragma unroll
                    for (int r = 0; r < 4; ++r) U0[(size_t)(row0 + r) * 512 + cl] = t4[r];
                } else if (sg == 1) {
#pragma unroll
                    for (int r = 0; r < 4; ++r) U1[(size_t)(row0 + r) * 512 + cl] = t4[r];
                    *(uint2*)&U2[(size_t)cl * BT_ + row0] = *(uint2*)t4;   // kkT
                } else {
#pragma unroll
                    for (int r = 0; r < 4; ++r) U3[(size_t)(row0 + r) * 512 + cl] = t4[r];
                }
            } else if (MODE == 5) {
                int sg = col >> 9, cl = col & 511;
                ushort_t t4[4];
#pragma unroll
                for (int r = 0; r < 4; ++r) t4[r] = f2bf(acc[i][j][r]);
                if (sg == 0) {
#pragma unroll
                    for (int r = 0; r < 4; ++r) U0[(size_t)(row0 + r) * 512 + cl] = t4[r];
                } else if (sg == 1) {
#pragma unroll
                    for (int r = 0; r < 4; ++r) U1[(size_t)(row0 + r) * 512 + cl] = t4[r];
                } else {
                    int bb = row0 / T_;
                    int t0 = row0 - bb * T_;
                    *(uint2*)&U2[((size_t)(bb * 512) + cl) * T_ + t0] = *(uint2*)t4;  // vhT
                }
            } else if (MODE == 1) {
                ushort_t t4[4];
#pragma unroll
                for (int r = 0; r < 4; ++r) {
                    size_t off = (size_t)(row0 + r) * 512 + col;
                    float z = acc[i][j][r];
                    F1[off] = z;
                    float h = bf2f(U1[off]) + siluf(z);
                    F0[off] = h;
                    ushort_t hb = f2bf(h);
                    U0[off] = hb;
                    t4[r] = hb;
                }
                *(uint2*)&U2[(size_t)col * BT_ + row0] = *(uint2*)t4;      // h1T
            } else if (MODE == 2) {
                ushort_t t4[4];
#pragma unroll
                for (int r = 0; r < 4; ++r) {
                    size_t off = (size_t)(row0 + r) * 512 + col;
                    float z = acc[i][j][r];
                    float s = 1.f / (1.f + expf(-z));
                    float d = c4[r] * (F0[off] + z * s - bf2f(U1[off]));
                    F1[off] = d;
                    ushort_t u = f2bf(d * (s * (1.f + z * (1.f - s))));
                    U0[off] = u;
                    t4[r] = u;
                }
                *(uint2*)&U2[(size_t)col * BT_ + row0] = *(uint2*)t4;      // dz1T
            } else if (MODE == 3) {
                ushort_t t4[4];
#pragma unroll
                for (int r = 0; r < 4; ++r) {
                    size_t off = (size_t)(row0 + r) * 512 + col;
                    float g = F0[off] + acc[i][j][r];
                    t4[r] = f2bf(g * dsiluf(F1[off]));
                }
                *(uint2*)&U0[(size_t)col * BT_ + row0] = *(uint2*)t4;      // dz0T
            } else if (MODE == 4) {
#pragma unroll
                for (int r = 0; r < 4; ++r) {
                    size_t off = (size_t)(row0 + r) * 512 + col;
                    U0[off] = f2bf(bf2f(U1[off]) + siluf(acc[i][j][r]));
                }
            } else if (MODE == 6) {
#pragma unroll
                for (int r = 0; r < 4; ++r) {
                    int row = row0 + r;
                    int bb = row / T_;
                    int t = row - bb * T_;
                    if (t >= M_) F0[((size_t)bb * S_ + (t - M_)) * 512 + col] = acc[i][j][r];
                }
            }
        }
    }
}

// ---------------- dW NT GEMM from T-major operands: C[m][n]=sum_t AT[m][t]*BT2[n][t], split-K x6 ----------------
__global__ __launch_bounds__(256)
void gemm_dw(const ushort_t* __restrict__ AT, const ushort_t* __restrict__ BT2,
             float* __restrict__ Cpart) {
    __shared__ ushort_t As[64 * 64];
    __shared__ ushort_t Bs[64 * 64];
    int tid = threadIdx.x;
    int m0 = blockIdx.x * 64, n0 = blockIdx.y * 64;
    int kbase = blockIdx.z * 704;
    int srow = tid >> 2;
    int sseg = (tid & 3) << 1;
    int wid = tid >> 6;
    int lane = tid & 63;
    int wm = (wid & 1) << 5;
    int wn = (wid >> 1) << 5;
    int fr = lane & 15;
    int fq = lane >> 4;
    int sw = srow & 7;
    const ushort_t* ga = AT  + (size_t)(m0 + srow) * BT_ + kbase + sseg * 8;
    const ushort_t* gb = BT2 + (size_t)(n0 + srow) * BT_ + kbase + sseg * 8;
    int4 av0 = *(const int4*)ga;
    int4 av1 = *(const int4*)(ga + 8);
    int4 bv0 = *(const int4*)gb;
    int4 bv1 = *(const int4*)(gb + 8);
    f32x4 acc[2][2] = {};
    for (int kt = 0; kt < 11; ++kt) {
        __syncthreads();
        *(int4*)&As[srow * 64 + ((sseg    ) ^ sw) * 8] = av0;
        *(int4*)&As[srow * 64 + ((sseg + 1) ^ sw) * 8] = av1;
        *(int4*)&Bs[srow * 64 + ((sseg    ) ^ sw) * 8] = bv0;
        *(int4*)&Bs[srow * 64 + ((sseg + 1) ^ sw) * 8] = bv1;
        __syncthreads();
        if (kt < 10) {
            int koff = (kt + 1) * 64;
            av0 = *(const int4*)(ga + koff);
            av1 = *(const int4*)(ga + koff + 8);
            bv0 = *(const int4*)(gb + koff);
            bv1 = *(const int4*)(gb + koff + 8);
        }
#pragma unroll
        for (int ks = 0; ks < 2; ++ks) {
            int seg = fq + ks * 4;
            int rA0 = wm + fr,      rA1 = wm + 16 + fr;
            int rB0 = wn + fr,      rB1 = wn + 16 + fr;
            s16x8 a0 = *(const s16x8*)&As[rA0 * 64 + (seg ^ (rA0 & 7)) * 8];
            s16x8 a1 = *(const s16x8*)&As[rA1 * 64 + (seg ^ (rA1 & 7)) * 8];
            s16x8 b0 = *(const s16x8*)&Bs[rB0 * 64 + (seg ^ (rB0 & 7)) * 8];
            s16x8 b1 = *(const s16x8*)&Bs[rB1 * 64 + (seg ^ (rB1 & 7)) * 8];
            acc[0][0] = __builtin_amdgcn_mfma_f32_16x16x32_bf16(a0, b0, acc[0][0], 0, 0, 0);
            acc[0][1] = __builtin_amdgcn_mfma_f32_16x16x32_bf16(a0, b1, acc[0][1], 0, 0, 0);
            acc[1][0] = __builtin_amdgcn_mfma_f32_16x16x32_bf16(a1, b0, acc[1][0], 0, 0, 0);
            acc[1][1] = __builtin_amdgcn_mfma_f32_16x16x32_bf16(a1, b1, acc[1][1], 0, 0, 0);
        }
    }
    float* C = Cpart + (size_t)blockIdx.z * 262144;
#pragma unroll
    for (int i = 0; i < 2; ++i)
#pragma unroll
        for (int j = 0; j < 2; ++j)
#pragma unroll
            for (int r = 0; r < 4; ++r)
                C[(size_t)(m0 + wm + i * 16 + fq * 4 + r) * 512 + n0 + wn + j * 16 + fr] =
                    acc[i][j][r];
}

// ---------------- AdamW first step (6 partial slices) -> bf16 weights ----------------
__global__ void adam_kernel(const float* __restrict__ W, const float* __restrict__ dWp,
                            ushort_t* __restrict__ Wnb) {
    int idx = blockIdx.x * 256 + threadIdx.x;
    int layer = idx >> 18;
    int i = idx & 262143;
    const float* base = dWp + (size_t)layer * 6 * 262144 + i;
    float g = 0.f;
#pragma unroll
    for (int z = 0; z < 6; ++z) g += base[(size_t)z * 262144];
    g *= (1.0f / 16.0f);
    float w = W[idx];
    float o = w * (1.0f - 1e-5f) - 1e-3f * g / (fabsf(g) + 1e-8f);
    Wnb[idx] = f2bf(o);
}

// ---------------- MFMA flash sliding-window attention (bf16 out, prefetched) ----------------
__global__ __launch_bounds__(256)
void swa_mfma(const ushort_t* __restrict__ qh, const ushort_t* __restrict__ kh,
              const ushort_t* __restrict__ vhT, ushort_t* __restrict__ ao) {
    __shared__ ushort_t Qs[64 * 64];
    __shared__ ushort_t Ks[64 * 64];
    __shared__ ushort_t Vs[64 * 64];
    __shared__ ushort_t Pw[4][16 * 72];
    int qt = 32 - (int)blockIdx.x;
    int hh = blockIdx.y;
    int b  = blockIdx.z;
    int tid = threadIdx.x;
    int wave = tid >> 6, lane = tid & 63;
    int fr = lane & 15, fq = lane >> 4;
    int tok = tid & 63, cs0 = tid >> 6;

    {
        const ushort_t* src = qh + ((size_t)(b * T_ + qt * 64 + tok)) * 512 + hh * 64;
#pragma unroll
        for (int p = 0; p < 2; ++p) {
            int seg = cs0 + p * 4;
            *(int4*)&Qs[tok * 64 + ((seg ^ (tok & 7)) << 3)] = *(const int4*)(src + seg * 8);
        }
    }
    __syncthreads();
    s16x8 qf0 = *(const s16x8*)&Qs[(wave * 16 + fr) * 64 + (((0 + fq) ^ (fr & 7)) << 3)];
    s16x8 qf1 = *(const s16x8*)&Qs[(wave * 16 + fr) * 64 + (((4 + fq) ^ (fr & 7)) << 3)];

    int i_q = qt * 64 + wave * 16 + fr;
    int iqmin = qt * 64 + wave * 16;
    float m_i = -1e30f, l_i = 0.f;
    f32x4 o[4] = {};
    int jstart = qt * 64 - (WIN_ - 1);
    if (jstart < 0) jstart = 0;
    jstart &= ~63;
    int jend = qt * 64;
    const ushort_t* kp = kh + ((size_t)(b * T_ + jstart + tok)) * 512 + hh * 64;
    const ushort_t* vp = vhT + ((size_t)(b * 512 + hh * 64 + tok)) * T_ + jstart;
    int4 ka = *(const int4*)(kp + cs0 * 8);
    int4 kb2 = *(const int4*)(kp + (cs0 + 4) * 8);
    int4 va = *(const int4*)(vp + cs0 * 8);
    int4 vb2 = *(const int4*)(vp + (cs0 + 4) * 8);
    for (int jb = jstart; jb <= jend; jb += 64) {
        __syncthreads();
        *(int4*)&Ks[tok * 64 + (((cs0    ) ^ (tok & 7)) << 3)] = ka;
        *(int4*)&Ks[tok * 64 + (((cs0 + 4) ^ (tok & 7)) << 3)] = kb2;
        *(int4*)&Vs[tok * 64 + (((cs0    ) ^ (tok & 7)) << 3)] = va;
        *(int4*)&Vs[tok * 64 + (((cs0 + 4) ^ (tok & 7)) << 3)] = vb2;
        __syncthreads();
        if (jb + 64 <= jend) {               // prefetch next K/V tile
            kp += 64 * 512;
            vp += 64;
            ka  = *(const int4*)(kp + cs0 * 8);
            kb2 = *(const int4*)(kp + (cs0 + 4) * 8);
            va  = *(const int4*)(vp + cs0 * 8);
            vb2 = *(const int4*)(vp + (cs0 + 4) * 8);
        }
        f32x4 sa[4] = {};
#pragma unroll
        for (int kf = 0; kf < 4; ++kf) {
            int krow = kf * 16 + fr;
            s16x8 a0 = *(const s16x8*)&Ks[krow * 64 + (((0 + fq) ^ (fr & 7)) << 3)];
            s16x8 a1 = *(const s16x8*)&Ks[krow * 64 + (((4 + fq) ^ (fr & 7)) << 3)];
            sa[kf] = __builtin_amdgcn_mfma_f32_16x16x32_bf16(a0, qf0, sa[kf], 0, 0, 0);
            sa[kf] = __builtin_amdgcn_mfma_f32_16x16x32_bf16(a1, qf1, sa[kf], 0, 0, 0);
        }
        float sv[16];
        float tmax = -1e30f;
        bool full = (jb + 63 <= iqmin) && (jb >= iqmin + 15 - (WIN_ - 1));
        if (full) {                           // interior tile: no mask work
#pragma unroll
            for (int kf = 0; kf < 4; ++kf)
#pragma unroll
                for (int r = 0; r < 4; ++r) {
                    float v = sa[kf][r] * 0.125f;
                    sv[kf * 4 + r] = v;
                    tmax = fmaxf(tmax, v);
                }
        } else {
#pragma unroll
            for (int kf = 0; kf < 4; ++kf)
#pragma unroll
                for (int r = 0; r < 4; ++r) {
                    int j2 = jb + kf * 16 + fq * 4 + r;
                    bool valid = (j2 <= i_q) && (i_q - j2 < WIN_);
                    float v = valid ? sa[kf][r] * 0.125f : -1e30f;
                    sv[kf * 4 + r] = v;
                    tmax = fmaxf(tmax, v);
                }
        }
        tmax = fmaxf(tmax, __shfl_xor(tmax, 16));
        tmax = fmaxf(tmax, __shfl_xor(tmax, 32));
        float mn = fmaxf(m_i, tmax);
        float alpha = __expf(m_i - mn);
        m_i = mn;
        float psum = 0.f;
#pragma unroll
        for (int kf = 0; kf < 4; ++kf)
#pragma unroll
            for (int r = 0; r < 4; ++r) {
                float v = sv[kf * 4 + r];
                float p = (v > -1e29f) ? __expf(v - mn) : 0.f;
                ushort_t pb = f2bf(p);
                psum += bf2f(pb);
                Pw[wave][fr * 72 + kf * 16 + fq * 4 + r] = pb;
            }
        psum += __shfl_xor(psum, 16);
        psum += __shfl_xor(psum, 32);
        l_i = l_i * alpha + psum;
        float a0s = __shfl(alpha, fq * 4 + 0);
        float a1s = __shfl(alpha, fq * 4 + 1);
        float a2s = __shfl(alpha, fq * 4 + 2);
        float a3s = __shfl(alpha, fq * 4 + 3);
#pragma unroll
        for (int nf = 0; nf < 4; ++nf) {
            o[nf][0] *= a0s; o[nf][1] *= a1s; o[nf][2] *= a2s; o[nf][3] *= a3s;
        }
#pragma unroll
        for (int ks = 0; ks < 2; ++ks) {
            s16x8 pa = *(const s16x8*)&Pw[wave][fr * 72 + ks * 32 + fq * 8];
#pragma unroll
            for (int nf = 0; nf < 4; ++nf) {
                int vrow = nf * 16 + fr;
                s16x8 bv = *(const s16x8*)&Vs[vrow * 64 + (((ks * 4 + fq) ^ (fr & 7)) << 3)];
                o[nf] = __builtin_amdgcn_mfma_f32_16x16x32_bf16(pa, bv, o[nf], 0, 0, 0);
            }
        }
    }
    float linv = 1.0f / l_i;
    float l0 = __shfl(linv, fq * 4 + 0);
    float l1 = __shfl(linv, fq * 4 + 1);
    float l2 = __shfl(linv, fq * 4 + 2);
    float l3 = __shfl(linv, fq * 4 + 3);
#pragma unroll
    for (int nf = 0; nf < 4; ++nf) {
        int col = hh * 64 + nf * 16 + fr;
        size_t row0 = (size_t)(b * T_) + qt * 64 + wave * 16 + fq * 4;
        ao[(row0 + 0) * 512 + col] = f2bf(o[nf][0] * l0);
        ao[(row0 + 1) * 512 + col] = f2bf(o[nf][1] * l1);
        ao[(row0 + 2) * 512 + col] = f2bf(o[nf][2] * l2);
        ao[(row0 + 3) * 512 + col] = f2bf(o[nf][3] * l3);
    }
}

extern "C" void kernel_launch(void* const* d_in, const int* in_sizes, int n_in,
                              void* d_out, int out_size, void* d_ws, size_t ws_size,
                              hipStream_t stream) {
    (void)in_sizes; (void)n_in; (void)out_size; (void)ws_size;
    const float* x      = (const float*)d_in[0];
    const float* meta   = (const float*)d_in[1];
    const float* lmm_w  = (const float*)d_in[2];
    const float* w_q    = (const float*)d_in[3];
    const float* w_k    = (const float*)d_in[4];
    const float* w_v    = (const float*)d_in[5];
    const float* w_lr   = (const float*)d_in[6];
    const float* swa_wq = (const float*)d_in[7];
    const float* swa_wk = (const float*)d_in[8];
    const float* swa_wv = (const float*)d_in[9];
    const float* swa_wo = (const float*)d_in[10];
    float* out = (float*)d_out;
    float* ws  = (float*)d_ws;

    const size_t BTD = (size_t)BT_ * D_;       // 2162688
    float* b4 = ws + 0 * BTD;                  // z0 f32
    float* b5 = ws + 1 * BTD;                  // h1 f32
    float* b7 = ws + 2 * BTD;                  // dp f32
    float* alr = ws + 3 * BTD;                 // BT_
    float* dWp = alr + BT_;                    // [2][6][262144] fp32
    ushort_t* xb = (ushort_t*)(dWp + 12 * 262144);
    ushort_t* B0 = xb + 0 * BTD;  // xm / dz0T / h1q
    ushort_t* B1 = xb + 1 * BTD;  // qq / qh
    ushort_t* B2 = xb + 2 * BTD;  // kk / ao
    ushort_t* B3 = xb + 3 * BTD;  // kkT
    ushort_t* B4 = xb + 4 * BTD;  // vv / r
    ushort_t* B5 = xb + 5 * BTD;  // h1_bf / kh
    ushort_t* B6 = xb + 6 * BTD;  // h1T / vhT
    ushort_t* B7 = xb + 7 * BTD;  // dz1
    ushort_t* B8 = xb + 8 * BTD;  // dz1T
    ushort_t* wbf = xb + 9 * BTD;
    ushort_t* wq_bf  = wbf + 0 * 262144;       // wq,wk,wv contiguous
    ushort_t* l0_bf  = wbf + 3 * 262144;
    ushort_t* l1_bf  = wbf + 4 * 262144;
    ushort_t* sq_bf  = wbf + 5 * 262144;       // sq,sk,sv contiguous
    ushort_t* wo_bf  = wbf + 8 * 262144;
    ushort_t* l1t_bf = wbf + 9 * 262144;
    ushort_t* wn_bf  = wbf + 10 * 262144;      // 2 layers

    dim3 blk(256);
    dim3 gg(66, 8);
    dim3 gq(66, 24);
    dim3 gdw(8, 8, 6);

    PrepArgs pa;
    pa.wsrc[0] = w_q;    pa.wdst[0] = wq_bf;
    pa.wsrc[1] = w_k;    pa.wdst[1] = wbf + 1 * 262144;
    pa.wsrc[2] = w_v;    pa.wdst[2] = wbf + 2 * 262144;
    pa.wsrc[3] = lmm_w;  pa.wdst[3] = l0_bf;
    pa.wsrc[4] = lmm_w + 262144; pa.wdst[4] = l1_bf;
    pa.wsrc[5] = swa_wq; pa.wdst[5] = sq_bf;
    pa.wsrc[6] = swa_wk; pa.wdst[6] = wbf + 6 * 262144;
    pa.wsrc[7] = swa_wv; pa.wdst[7] = wbf + 7 * 262144;
    pa.wsrc[8] = swa_wo; pa.wdst[8] = wo_bf;
    pa.l1src = lmm_w + 262144; pa.l1t = l1t_bf;
    pa.x = x; pa.meta = meta; pa.xm = B0;
    pa.wlr = w_lr; pa.alr = alr;

    prep_kernel<<<dim3(3520), blk, 0, stream>>>(pa);
    // qq/kk(+kkT)/vv = xm @ {wq,wk,wv}^T
    mgemm<0><<<gq, blk, 0, stream>>>(B0, wq_bf, nullptr, nullptr, B1, B2, B3, B4, nullptr);
    // z0=b4, h1=b5 + h1_bf(B5) + h1T(B6); residual kk(B2)
    mgemm<1><<<gg, blk, 0, stream>>>(B2, l0_bf, b5, b4, B5, B2, B6, nullptr, nullptr);
    // z1 -> dp=b7, dz1(B7), dz1T(B8); reads h1=b5, v=B4, alr
    mgemm<2><<<gg, blk, 0, stream>>>(B5, l1_bf, b5, b7, B7, B4, B8, nullptr, alr);
    // dh1 = dp + dz1@l1 -> dz0T(B0); reads dp=b7, z0=b4
    mgemm<3><<<gg, blk, 0, stream>>>(B7, l1t_bf, b7, b4, B0, nullptr, nullptr, nullptr, nullptr);
    gemm_dw<<<gdw, blk, 0, stream>>>(B8, B6, dWp + 6 * 262144);   // dW1 = dz1T x h1T
    gemm_dw<<<gdw, blk, 0, stream>>>(B0, B3, dWp);                // dW0 = dz0T x kkT
    adam_kernel<<<dim3(2048), blk, 0, stream>>>(lmm_w, dWp, wn_bf);
    // h1q(B0) = qq + silu(qq@Wn0^T)
    mgemm<4><<<gg, blk, 0, stream>>>(B1, wn_bf, nullptr, nullptr, B0, B1, nullptr, nullptr, nullptr);
    // r(B4) = h1q + silu(h1q@Wn1^T)
    mgemm<4><<<gg, blk, 0, stream>>>(B0, wn_bf + 262144, nullptr, nullptr, B4, B0, nullptr, nullptr, nullptr);
    // qh(B1)/kh(B5)/vhT(B6) = r @ {sq,sk,sv}^T
    mgemm<5><<<gq, blk, 0, stream>>>(B4, sq_bf, nullptr, nullptr, B1, B5, B6, nullptr, nullptr);
    swa_mfma<<<dim3(33, 8, 2), blk, 0, stream>>>(B1, B5, B6, B2); // ao(B2)
    // out = ao @ wo^T (row-filtered fp32)
    mgemm<6><<<gg, blk, 0, stream>>>(B2, wo_bf, out, nullptr, nullptr, nullptr, nullptr, nullptr, nullptr);
}

// Round 6
// 209.071 us; speedup vs baseline: 4.1579x; 1.0406x over previous
//
#include <hip/hip_runtime.h>
#include <hip/hip_bf16.h>

#define B_   2
#define S_   2048
#define D_   512
#define M_   64
#define T_   2112
#define BT_  4224
#define H_   8
#define WIN_ 512

typedef short s16x8 __attribute__((ext_vector_type(8)));
typedef float f32x4 __attribute__((ext_vector_type(4)));
typedef unsigned short ushort_t;

__device__ __forceinline__ float siluf(float x) {
    float s = 1.0f / (1.0f + expf(-x));
    return x * s;
}
__device__ __forceinline__ float dsiluf(float x) {
    float s = 1.0f / (1.0f + expf(-x));
    return s * (1.0f + x * (1.0f - s));
}
__device__ __forceinline__ float bf2f(ushort_t u) {
    union { float f; unsigned int i; } x; x.i = ((unsigned int)u) << 16; return x.f;
}
__device__ __forceinline__ ushort_t f2bf(float f) {
    union { float f; unsigned int i; } x; x.f = f;
    unsigned int r = x.i + 0x7FFFu + ((x.i >> 16) & 1u);
    return (ushort_t)(r >> 16);
}
__device__ __forceinline__ void pack8(ushort_t* dst, const float* v) {
    ushort_t tmp[8];
#pragma unroll
    for (int i = 0; i < 8; ++i) tmp[i] = f2bf(v[i]);
    *(int4*)dst = *(const int4*)tmp;
}

// ---------------- fused prep: weight cvt (9), l1 transpose, xm build, alr ----------------
struct PrepArgs {
    const float* wsrc[9]; ushort_t* wdst[9];
    const float* l1src;   ushort_t* l1t;
    const float* x; const float* meta; ushort_t* xm;
    const float* wlr; float* alr;
};
__global__ __launch_bounds__(256)
void prep_kernel(PrepArgs p) {
    __shared__ float tbuf[32][33];
    int bid = blockIdx.x;
    int tid = threadIdx.x;
    if (bid < 1152) {                       // weight cvt: 9 x 128 blocks
        int w = bid >> 7;
        int idx = ((bid & 127) << 8) + tid;
        const float* src = p.wsrc[w] + (size_t)idx * 8;
        float v[8];
        *(float4*)&v[0] = *(const float4*)src;
        *(float4*)&v[4] = *(const float4*)(src + 4);
        pack8(p.wdst[w] + (size_t)idx * 8, v);
    } else if (bid < 1408) {                // l1 transpose: 256 blocks
        int wz = bid - 1152;
        int bx = wz & 15, by = wz >> 4;
        int tr = tid >> 3, tc = (tid & 7) * 4;
        int r0 = by * 32, c0 = bx * 32;
        *(float4*)&tbuf[tr][tc] = *(const float4*)&p.l1src[(size_t)(r0 + tr) * 512 + c0 + tc];
        __syncthreads();
        ushort_t o[4];
#pragma unroll
        for (int i = 0; i < 4; ++i) o[i] = f2bf(tbuf[tc + i][tr]);
        *(ushort2*)&p.l1t[(size_t)(c0 + tr) * 512 + r0 + tc] = *(ushort2*)&o[0];
        *(ushort2*)&p.l1t[(size_t)(c0 + tr) * 512 + r0 + tc + 2] = *(ushort2*)&o[2];
    } else if (bid < 2464) {                // xm build: 1056 blocks, 8-elem groups
        int idx = (bid - 1408) * 256 + tid;
        int seg = idx & 63;
        int row = idx >> 6;
        int b = row / T_;
        int t = row - b * T_;
        const float* src;
        if (t < M_) src = p.meta + (size_t)t * 512 + seg * 8;
        else        src = p.x + ((size_t)b * S_ + (t - M_)) * 512 + seg * 8;
        float v[8];
        *(float4*)&v[0] = *(const float4*)src;
        *(float4*)&v[4] = *(const float4*)(src + 4);
        pack8(p.xm + (size_t)row * 512 + seg * 8, v);
    } else {                                // alr: 1056 blocks x 4 rows (f32 sources)
        int r = (bid - 2464) * 4 + (tid >> 6);
        int lane = tid & 63;
        int b = r / T_;
        int t = r - b * T_;
        const float* row = (t < M_) ? (p.meta + (size_t)t * 512)
                                    : (p.x + ((size_t)b * S_ + (t - M_)) * 512);
        float s = 0.f;
#pragma unroll
        for (int k = 0; k < 8; ++k) s = fmaf(row[lane + k * 64], p.wlr[lane + k * 64], s);
#pragma unroll
        for (int off = 32; off >= 1; off >>= 1) s += __shfl_xor(s, off, 64);
        if (lane == 0) p.alr[r] = 0.01f / (1.0f + expf(-s));
    }
}

// ---------------- bf16 MFMA GEMM (K=512) with fused epilogues, reg-prefetch pipeline ----------------
// MODE 0 QKV (N=1536: qq->U0, kk->U1 + kkT->U2, vv->U3)
// MODE 1 H1  (h1 bf->U0 + h1T->U2, dsilu(z0) bf->U3; residual kk=U1)
// MODE 2 Z1DP(dz1->U0 + dz1T->U2, dp bf->U4; reads h1b=U1, v=U3, alr)
// MODE 3 DH1DZ0 (dz0 T-major->U0; reads dp=U1, dsz0=U2)
// MODE 4 RES2 (U0 = bf(U1)+silu(acc))
// MODE 5 SWAQKV (N=1536: qh->U0, kh->U1, vhT per-batch transposed->U2)
// MODE 6 WO (row-filtered fp32 out->F0)
template<int MODE>
__global__ __launch_bounds__(256)
void mgemm(const ushort_t* __restrict__ A, const ushort_t* __restrict__ Bt,
           float* __restrict__ F0,
           ushort_t* __restrict__ U0, ushort_t* __restrict__ U1,
           ushort_t* __restrict__ U2, ushort_t* __restrict__ U3,
           ushort_t* __restrict__ U4,
           const float* __restrict__ alrp) {
    __shared__ ushort_t As[64 * 64];
    __shared__ ushort_t Bs[64 * 64];
    int tid = threadIdx.x;
    int m0 = blockIdx.x * 64, n0 = blockIdx.y * 64;
    int srow = tid >> 2;
    int sseg = (tid & 3) << 1;
    int wid = tid >> 6;
    int lane = tid & 63;
    int wm = (wid & 1) << 5;
    int wn = (wid >> 1) << 5;
    int fr = lane & 15;
    int fq = lane >> 4;
    int sw = srow & 7;
    const ushort_t* ga = A  + (size_t)(m0 + srow) * 512 + sseg * 8;
    const ushort_t* gb = Bt + (size_t)(n0 + srow) * 512 + sseg * 8;
    int4 av0 = *(const int4*)ga;
    int4 av1 = *(const int4*)(ga + 8);
    int4 bv0 = *(const int4*)gb;
    int4 bv1 = *(const int4*)(gb + 8);
    f32x4 acc[2][2] = {};
    for (int k0 = 0; k0 < 512; k0 += 64) {
        __syncthreads();
        *(int4*)&As[srow * 64 + ((sseg    ) ^ sw) * 8] = av0;
        *(int4*)&As[srow * 64 + ((sseg + 1) ^ sw) * 8] = av1;
        *(int4*)&Bs[srow * 64 + ((sseg    ) ^ sw) * 8] = bv0;
        *(int4*)&Bs[srow * 64 + ((sseg + 1) ^ sw) * 8] = bv1;
        __syncthreads();
        if (k0 + 64 < 512) {
            av0 = *(const int4*)(ga + k0 + 64);
            av1 = *(const int4*)(ga + k0 + 72);
            bv0 = *(const int4*)(gb + k0 + 64);
            bv1 = *(const int4*)(gb + k0 + 72);
        }
#pragma unroll
        for (int ks = 0; ks < 2; ++ks) {
            int seg = fq + ks * 4;
            int rA0 = wm + fr,      rA1 = wm + 16 + fr;
            int rB0 = wn + fr,      rB1 = wn + 16 + fr;
            s16x8 a0 = *(const s16x8*)&As[rA0 * 64 + (seg ^ (rA0 & 7)) * 8];
            s16x8 a1 = *(const s16x8*)&As[rA1 * 64 + (seg ^ (rA1 & 7)) * 8];
            s16x8 b0 = *(const s16x8*)&Bs[rB0 * 64 + (seg ^ (rB0 & 7)) * 8];
            s16x8 b1 = *(const s16x8*)&Bs[rB1 * 64 + (seg ^ (rB1 & 7)) * 8];
            acc[0][0] = __builtin_amdgcn_mfma_f32_16x16x32_bf16(a0, b0, acc[0][0], 0, 0, 0);
            acc[0][1] = __builtin_amdgcn_mfma_f32_16x16x32_bf16(a0, b1, acc[0][1], 0, 0, 0);
            acc[1][0] = __builtin_amdgcn_mfma_f32_16x16x32_bf16(a1, b0, acc[1][0], 0, 0, 0);
            acc[1][1] = __builtin_amdgcn_mfma_f32_16x16x32_bf16(a1, b1, acc[1][1], 0, 0, 0);
        }
    }
#pragma unroll
    for (int i = 0; i < 2; ++i) {
        int row0 = m0 + wm + i * 16 + fq * 4;
        float c4[4];
        if (MODE == 2) {
#pragma unroll
            for (int r = 0; r < 4; ++r) c4[r] = (2.0f / 512.0f) * alrp[row0 + r];
        }
#pragma unroll
        for (int j = 0; j < 2; ++j) {
            int col = n0 + wn + j * 16 + fr;
            if (MODE == 0) {
                int sg = col >> 9, cl = col & 511;
                ushort_t t4[4];
#pragma unroll
                for (int r = 0; r < 4; ++r) t4[r] = f2bf(acc[i][j][r]);
                if (sg == 0) {
#pragma unroll
                    for (int r = 0; r < 4; ++r) U0[(size_t)(row0 + r) * 512 + cl] = t4[r];
                } else if (sg == 1) {
#pragma unroll
                    for (int r = 0; r < 4; ++r) U1[(size_t)(row0 + r) * 512 + cl] = t4[r];
                    *(uint2*)&U2[(size_t)cl * BT_ + row0] = *(uint2*)t4;   // kkT
                } else {
#pragma unroll
                    for (int r = 0; r < 4; ++r) U3[(size_t)(row0 + r) * 512 + cl] = t4[r];
                }
            } else if (MODE == 5) {
                int sg = col >> 9, cl = col & 511;
                ushort_t t4[4];
#pragma unroll
                for (int r = 0; r < 4; ++r) t4[r] = f2bf(acc[i][j][r]);
                if (sg == 0) {
#pragma unroll
                    for (int r = 0; r < 4; ++r) U0[(size_t)(row0 + r) * 512 + cl] = t4[r];
                } else if (sg == 1) {
#pragma unroll
                    for (int r = 0; r < 4; ++r) U1[(size_t)(row0 + r) * 512 + cl] = t4[r];
                } else {
                    int bb = row0 / T_;
                    int t0 = row0 - bb * T_;
                    *(uint2*)&U2[((size_t)(bb * 512) + cl) * T_ + t0] = *(uint2*)t4;  // vhT
                }
            } else if (MODE == 1) {
                ushort_t t4[4];
#pragma unroll
                for (int r = 0; r < 4; ++r) {
                    size_t off = (size_t)(row0 + r) * 512 + col;
                    float z = acc[i][j][r];
                    float h = bf2f(U1[off]) + siluf(z);
                    ushort_t hb = f2bf(h);
                    U0[off] = hb;
                    t4[r] = hb;
                    U3[off] = f2bf(dsiluf(z));                             // dsilu(z0)
                }
                *(uint2*)&U2[(size_t)col * BT_ + row0] = *(uint2*)t4;      // h1T
            } else if (MODE == 2) {
                ushort_t t4[4];
#pragma unroll
                for (int r = 0; r < 4; ++r) {
                    size_t off = (size_t)(row0 + r) * 512 + col;
                    float z = acc[i][j][r];
                    float s = 1.f / (1.f + expf(-z));
                    float d = c4[r] * (bf2f(U1[off]) + z * s - bf2f(U3[off]));
                    U4[off] = f2bf(d);                                     // dp
                    ushort_t u = f2bf(d * (s * (1.f + z * (1.f - s))));
                    U0[off] = u;
                    t4[r] = u;
                }
                *(uint2*)&U2[(size_t)col * BT_ + row0] = *(uint2*)t4;      // dz1T
            } else if (MODE == 3) {
                ushort_t t4[4];
#pragma unroll
                for (int r = 0; r < 4; ++r) {
                    size_t off = (size_t)(row0 + r) * 512 + col;
                    float g = bf2f(U1[off]) + acc[i][j][r];
                    t4[r] = f2bf(g * bf2f(U2[off]));
                }
                *(uint2*)&U0[(size_t)col * BT_ + row0] = *(uint2*)t4;      // dz0T
            } else if (MODE == 4) {
#pragma unroll
                for (int r = 0; r < 4; ++r) {
                    size_t off = (size_t)(row0 + r) * 512 + col;
                    U0[off] = f2bf(bf2f(U1[off]) + siluf(acc[i][j][r]));
                }
            } else if (MODE == 6) {
#pragma unroll
                for (int r = 0; r < 4; ++r) {
                    int row = row0 + r;
                    int bb = row / T_;
                    int t = row - bb * T_;
                    if (t >= M_) F0[((size_t)bb * S_ + (t - M_)) * 512 + col] = acc[i][j][r];
                }
            }
        }
    }
}

// ---------------- combined dW NT GEMM (both layers): z in [0,12), layer = z/6 ----------------
__global__ __launch_bounds__(256)
void gemm_dw2(const ushort_t* __restrict__ A1T, const ushort_t* __restrict__ B1T,
              const ushort_t* __restrict__ A0T, const ushort_t* __restrict__ B0T,
              float* __restrict__ Cpart) {
    __shared__ ushort_t As[64 * 64];
    __shared__ ushort_t Bs[64 * 64];
    int tid = threadIdx.x;
    int zz = blockIdx.z;
    int layer = (zz >= 6);
    int slice = layer ? (zz - 6) : zz;
    const ushort_t* AT  = layer ? A1T : A0T;
    const ushort_t* BT2 = layer ? B1T : B0T;
    int m0 = blockIdx.x * 64, n0 = blockIdx.y * 64;
    int kbase = slice * 704;
    int srow = tid >> 2;
    int sseg = (tid & 3) << 1;
    int wid = tid >> 6;
    int lane = tid & 63;
    int wm = (wid & 1) << 5;
    int wn = (wid >> 1) << 5;
    int fr = lane & 15;
    int fq = lane >> 4;
    int sw = srow & 7;
    const ushort_t* ga = AT  + (size_t)(m0 + srow) * BT_ + kbase + sseg * 8;
    const ushort_t* gb = BT2 + (size_t)(n0 + srow) * BT_ + kbase + sseg * 8;
    int4 av0 = *(const int4*)ga;
    int4 av1 = *(const int4*)(ga + 8);
    int4 bv0 = *(const int4*)gb;
    int4 bv1 = *(const int4*)(gb + 8);
    f32x4 acc[2][2] = {};
    for (int kt = 0; kt < 11; ++kt) {
        __syncthreads();
        *(int4*)&As[srow * 64 + ((sseg    ) ^ sw) * 8] = av0;
        *(int4*)&As[srow * 64 + ((sseg + 1) ^ sw) * 8] = av1;
        *(int4*)&Bs[srow * 64 + ((sseg    ) ^ sw) * 8] = bv0;
        *(int4*)&Bs[srow * 64 + ((sseg + 1) ^ sw) * 8] = bv1;
        __syncthreads();
        if (kt < 10) {
            int koff = (kt + 1) * 64;
            av0 = *(const int4*)(ga + koff);
            av1 = *(const int4*)(ga + koff + 8);
            bv0 = *(const int4*)(gb + koff);
            bv1 = *(const int4*)(gb + koff + 8);
        }
#pragma unroll
        for (int ks = 0; ks < 2; ++ks) {
            int seg = fq + ks * 4;
            int rA0 = wm + fr,      rA1 = wm + 16 + fr;
            int rB0 = wn + fr,      rB1 = wn + 16 + fr;
            s16x8 a0 = *(const s16x8*)&As[rA0 * 64 + (seg ^ (rA0 & 7)) * 8];
            s16x8 a1 = *(const s16x8*)&As[rA1 * 64 + (seg ^ (rA1 & 7)) * 8];
            s16x8 b0 = *(const s16x8*)&Bs[rB0 * 64 + (seg ^ (rB0 & 7)) * 8];
            s16x8 b1 = *(const s16x8*)&Bs[rB1 * 64 + (seg ^ (rB1 & 7)) * 8];
            acc[0][0] = __builtin_amdgcn_mfma_f32_16x16x32_bf16(a0, b0, acc[0][0], 0, 0, 0);
            acc[0][1] = __builtin_amdgcn_mfma_f32_16x16x32_bf16(a0, b1, acc[0][1], 0, 0, 0);
            acc[1][0] = __builtin_amdgcn_mfma_f32_16x16x32_bf16(a1, b0, acc[1][0], 0, 0, 0);
            acc[1][1] = __builtin_amdgcn_mfma_f32_16x16x32_bf16(a1, b1, acc[1][1], 0, 0, 0);
        }
    }
    float* C = Cpart + (size_t)zz * 262144;
#pragma unroll
    for (int i = 0; i < 2; ++i)
#pragma unroll
        for (int j = 0; j < 2; ++j)
#pragma unroll
            for (int r = 0; r < 4; ++r)
                C[(size_t)(m0 + wm + i * 16 + fq * 4 + r) * 512 + n0 + wn + j * 16 + fr] =
                    acc[i][j][r];
}

// ---------------- AdamW first step (6 partial slices per layer) -> bf16 weights ----------------
__global__ void adam_kernel(const float* __restrict__ W, const float* __restrict__ dWp,
                            ushort_t* __restrict__ Wnb) {
    int idx = blockIdx.x * 256 + threadIdx.x;
    int layer = idx >> 18;
    int i = idx & 262143;
    const float* base = dWp + (size_t)layer * 6 * 262144 + i;
    float g = 0.f;
#pragma unroll
    for (int z = 0; z < 6; ++z) g += base[(size_t)z * 262144];
    g *= (1.0f / 16.0f);
    float w = W[idx];
    float o = w * (1.0f - 1e-5f) - 1e-3f * g / (fabsf(g) + 1e-8f);
    Wnb[idx] = f2bf(o);
}

// ---------------- MFMA flash SWA, unnormalized softmax (scores bounded) ----------------
__global__ __launch_bounds__(256)
void swa_mfma(const ushort_t* __restrict__ qh, const ushort_t* __restrict__ kh,
              const ushort_t* __restrict__ vhT, ushort_t* __restrict__ ao) {
    __shared__ ushort_t Qs[64 * 64];
    __shared__ ushort_t Ks[64 * 64];
    __shared__ ushort_t Vs[64 * 64];
    __shared__ ushort_t Pw[4][16 * 72];
    int qt = 32 - (int)blockIdx.x;
    int hh = blockIdx.y;
    int b  = blockIdx.z;
    int tid = threadIdx.x;
    int wave = tid >> 6, lane = tid & 63;
    int fr = lane & 15, fq = lane >> 4;
    int tok = tid & 63, cs0 = tid >> 6;

    {
        const ushort_t* src = qh + ((size_t)(b * T_ + qt * 64 + tok)) * 512 + hh * 64;
#pragma unroll
        for (int p = 0; p < 2; ++p) {
            int seg = cs0 + p * 4;
            *(int4*)&Qs[tok * 64 + ((seg ^ (tok & 7)) << 3)] = *(const int4*)(src + seg * 8);
        }
    }
    __syncthreads();
    s16x8 qf0 = *(const s16x8*)&Qs[(wave * 16 + fr) * 64 + (((0 + fq) ^ (fr & 7)) << 3)];
    s16x8 qf1 = *(const s16x8*)&Qs[(wave * 16 + fr) * 64 + (((4 + fq) ^ (fr & 7)) << 3)];

    int i_q = qt * 64 + wave * 16 + fr;
    int iqmin = qt * 64 + wave * 16;
    float l_i = 0.f;
    f32x4 o[4] = {};
    int jstart = qt * 64 - (WIN_ - 1);
    if (jstart < 0) jstart = 0;
    jstart &= ~63;
    int jend = qt * 64;
    const ushort_t* kp = kh + ((size_t)(b * T_ + jstart + tok)) * 512 + hh * 64;
    const ushort_t* vp = vhT + ((size_t)(b * 512 + hh * 64 + tok)) * T_ + jstart;
    int4 ka = *(const int4*)(kp + cs0 * 8);
    int4 kb2 = *(const int4*)(kp + (cs0 + 4) * 8);
    int4 va = *(const int4*)(vp + cs0 * 8);
    int4 vb2 = *(const int4*)(vp + (cs0 + 4) * 8);
    for (int jb = jstart; jb <= jend; jb += 64) {
        __syncthreads();
        *(int4*)&Ks[tok * 64 + (((cs0    ) ^ (tok & 7)) << 3)] = ka;
        *(int4*)&Ks[tok * 64 + (((cs0 + 4) ^ (tok & 7)) << 3)] = kb2;
        *(int4*)&Vs[tok * 64 + (((cs0    ) ^ (tok & 7)) << 3)] = va;
        *(int4*)&Vs[tok * 64 + (((cs0 + 4) ^ (tok & 7)) << 3)] = vb2;
        __syncthreads();
        if (jb + 64 <= jend) {
            kp += 64 * 512;
            vp += 64;
            ka  = *(const int4*)(kp + cs0 * 8);
            kb2 = *(const int4*)(kp + (cs0 + 4) * 8);
            va  = *(const int4*)(vp + cs0 * 8);
            vb2 = *(const int4*)(vp + (cs0 + 4) * 8);
        }
        f32x4 sa[4] = {};
#pragma unroll
        for (int kf = 0; kf < 4; ++kf) {
            int krow = kf * 16 + fr;
            s16x8 a0 = *(const s16x8*)&Ks[krow * 64 + (((0 + fq) ^ (fr & 7)) << 3)];
            s16x8 a1 = *(const s16x8*)&Ks[krow * 64 + (((4 + fq) ^ (fr & 7)) << 3)];
            sa[kf] = __builtin_amdgcn_mfma_f32_16x16x32_bf16(a0, qf0, sa[kf], 0, 0, 0);
            sa[kf] = __builtin_amdgcn_mfma_f32_16x16x32_bf16(a1, qf1, sa[kf], 0, 0, 0);
        }
        float psum = 0.f;
        bool full = (jb + 63 <= iqmin) && (jb >= iqmin + 15 - (WIN_ - 1));
        if (full) {
#pragma unroll
            for (int kf = 0; kf < 4; ++kf)
#pragma unroll
                for (int r = 0; r < 4; ++r) {
                    float p = __expf(sa[kf][r] * 0.125f);
                    ushort_t pb = f2bf(p);
                    psum += bf2f(pb);
                    Pw[wave][fr * 72 + kf * 16 + fq * 4 + r] = pb;
                }
        } else {
#pragma unroll
            for (int kf = 0; kf < 4; ++kf)
#pragma unroll
                for (int r = 0; r < 4; ++r) {
                    int j2 = jb + kf * 16 + fq * 4 + r;
                    bool valid = (j2 <= i_q) && (i_q - j2 < WIN_);
                    float p = valid ? __expf(sa[kf][r] * 0.125f) : 0.f;
                    ushort_t pb = f2bf(p);
                    psum += bf2f(pb);
                    Pw[wave][fr * 72 + kf * 16 + fq * 4 + r] = pb;
                }
        }
        psum += __shfl_xor(psum, 16);
        psum += __shfl_xor(psum, 32);
        l_i += psum;
#pragma unroll
        for (int ks = 0; ks < 2; ++ks) {
            s16x8 pa = *(const s16x8*)&Pw[wave][fr * 72 + ks * 32 + fq * 8];
#pragma unroll
            for (int nf = 0; nf < 4; ++nf) {
                int vrow = nf * 16 + fr;
                s16x8 bv = *(const s16x8*)&Vs[vrow * 64 + (((ks * 4 + fq) ^ (fr & 7)) << 3)];
                o[nf] = __builtin_amdgcn_mfma_f32_16x16x32_bf16(pa, bv, o[nf], 0, 0, 0);
            }
        }
    }
    float linv = 1.0f / l_i;
    float l0 = __shfl(linv, fq * 4 + 0);
    float l1 = __shfl(linv, fq * 4 + 1);
    float l2 = __shfl(linv, fq * 4 + 2);
    float l3 = __shfl(linv, fq * 4 + 3);
#pragma unroll
    for (int nf = 0; nf < 4; ++nf) {
        int col = hh * 64 + nf * 16 + fr;
        size_t row0 = (size_t)(b * T_) + qt * 64 + wave * 16 + fq * 4;
        ao[(row0 + 0) * 512 + col] = f2bf(o[nf][0] * l0);
        ao[(row0 + 1) * 512 + col] = f2bf(o[nf][1] * l1);
        ao[(row0 + 2) * 512 + col] = f2bf(o[nf][2] * l2);
        ao[(row0 + 3) * 512 + col] = f2bf(o[nf][3] * l3);
    }
}

extern "C" void kernel_launch(void* const* d_in, const int* in_sizes, int n_in,
                              void* d_out, int out_size, void* d_ws, size_t ws_size,
                              hipStream_t stream) {
    (void)in_sizes; (void)n_in; (void)out_size; (void)ws_size;
    const float* x      = (const float*)d_in[0];
    const float* meta   = (const float*)d_in[1];
    const float* lmm_w  = (const float*)d_in[2];
    const float* w_q    = (const float*)d_in[3];
    const float* w_k    = (const float*)d_in[4];
    const float* w_v    = (const float*)d_in[5];
    const float* w_lr   = (const float*)d_in[6];
    const float* swa_wq = (const float*)d_in[7];
    const float* swa_wk = (const float*)d_in[8];
    const float* swa_wv = (const float*)d_in[9];
    const float* swa_wo = (const float*)d_in[10];
    float* out = (float*)d_out;
    float* ws  = (float*)d_ws;

    const size_t BTD = (size_t)BT_ * D_;       // 2162688
    float* alr = ws;                           // BT_
    float* dWp = alr + BT_;                    // [2][6][262144] fp32
    ushort_t* xb = (ushort_t*)(dWp + 12 * 262144);
    ushort_t* B0  = xb + 0 * BTD;   // xm / dz0T / h1q
    ushort_t* B1  = xb + 1 * BTD;   // qq / qh
    ushort_t* B2  = xb + 2 * BTD;   // kk / ao
    ushort_t* B3  = xb + 3 * BTD;   // kkT
    ushort_t* B4  = xb + 4 * BTD;   // vv / r
    ushort_t* B5  = xb + 5 * BTD;   // h1b / kh
    ushort_t* B6  = xb + 6 * BTD;   // h1T / vhT
    ushort_t* B7  = xb + 7 * BTD;   // dz1
    ushort_t* B8  = xb + 8 * BTD;   // dz1T
    ushort_t* B9  = xb + 9 * BTD;   // dp bf
    ushort_t* B10 = xb + 10 * BTD;  // dsilu(z0) bf
    ushort_t* wbf = xb + 11 * BTD;
    ushort_t* wq_bf  = wbf + 0 * 262144;       // wq,wk,wv contiguous
    ushort_t* l0_bf  = wbf + 3 * 262144;
    ushort_t* l1_bf  = wbf + 4 * 262144;
    ushort_t* sq_bf  = wbf + 5 * 262144;       // sq,sk,sv contiguous
    ushort_t* wo_bf  = wbf + 8 * 262144;
    ushort_t* l1t_bf = wbf + 9 * 262144;
    ushort_t* wn_bf  = wbf + 10 * 262144;      // 2 layers

    dim3 blk(256);
    dim3 gg(66, 8);
    dim3 gq(66, 24);
    dim3 gdw(8, 8, 12);

    PrepArgs pa;
    pa.wsrc[0] = w_q;    pa.wdst[0] = wq_bf;
    pa.wsrc[1] = w_k;    pa.wdst[1] = wbf + 1 * 262144;
    pa.wsrc[2] = w_v;    pa.wdst[2] = wbf + 2 * 262144;
    pa.wsrc[3] = lmm_w;  pa.wdst[3] = l0_bf;
    pa.wsrc[4] = lmm_w + 262144; pa.wdst[4] = l1_bf;
    pa.wsrc[5] = swa_wq; pa.wdst[5] = sq_bf;
    pa.wsrc[6] = swa_wk; pa.wdst[6] = wbf + 6 * 262144;
    pa.wsrc[7] = swa_wv; pa.wdst[7] = wbf + 7 * 262144;
    pa.wsrc[8] = swa_wo; pa.wdst[8] = wo_bf;
    pa.l1src = lmm_w + 262144; pa.l1t = l1t_bf;
    pa.x = x; pa.meta = meta; pa.xm = B0;
    pa.wlr = w_lr; pa.alr = alr;

    prep_kernel<<<dim3(3520), blk, 0, stream>>>(pa);
    // qq(B1)/kk(B2)+kkT(B3)/vv(B4) = xm @ {wq,wk,wv}^T
    mgemm<0><<<gq, blk, 0, stream>>>(B0, wq_bf, nullptr, B1, B2, B3, B4, nullptr, nullptr);
    // h1b(B5)+h1T(B6), dsz0(B10); residual kk(B2)
    mgemm<1><<<gg, blk, 0, stream>>>(B2, l0_bf, nullptr, B5, B2, B6, B10, nullptr, nullptr);
    // dz1(B7)+dz1T(B8), dp(B9); reads h1b(B5), v(B4), alr
    mgemm<2><<<gg, blk, 0, stream>>>(B5, l1_bf, nullptr, B7, B5, B8, B4, B9, alr);
    // dz0T(B0); reads dp(B9), dsz0(B10)
    mgemm<3><<<gg, blk, 0, stream>>>(B7, l1t_bf, nullptr, B0, B9, B10, nullptr, nullptr, nullptr);
    // dW1 = dz1T x h1T (z 6..11), dW0 = dz0T x kkT (z 0..5)
    gemm_dw2<<<gdw, blk, 0, stream>>>(B8, B6, B0, B3, dWp);
    adam_kernel<<<dim3(2048), blk, 0, stream>>>(lmm_w, dWp, wn_bf);
    // h1q(B0) = qq + silu(qq@Wn0^T)
    mgemm<4><<<gg, blk, 0, stream>>>(B1, wn_bf, nullptr, B0, B1, nullptr, nullptr, nullptr, nullptr);
    // r(B4) = h1q + silu(h1q@Wn1^T)
    mgemm<4><<<gg, blk, 0, stream>>>(B0, wn_bf + 262144, nullptr, B4, B0, nullptr, nullptr, nullptr, nullptr);
    // qh(B1)/kh(B5)/vhT(B6) = r @ {sq,sk,sv}^T
    mgemm<5><<<gq, blk, 0, stream>>>(B4, sq_bf, nullptr, B1, B5, B6, nullptr, nullptr, nullptr);
    swa_mfma<<<dim3(33, 8, 2), blk, 0, stream>>>(B1, B5, B6, B2); // ao(B2)
    // out = ao @ wo^T (row-filtered fp32)
    mgemm<6><<<gg, blk, 0, stream>>>(B2, wo_bf, out, nullptr, nullptr, nullptr, nullptr, nullptr, nullptr);
}